// Round 1
// baseline (1512.773 us; speedup 1.0000x reference)
//
#include <hip/hip_runtime.h>
#include <hip/hip_bf16.h>
#include <math.h>

// Problem constants
#define PB 8
#define PL 1024
#define PC 1024
#define PH 16
#define PD 64
#define MAX_SCALE_MUL 4.605170185988092f  // log(100)

// ---------------------------------------------------------------------------
// Kernel 1: QKV GEMM.  qkv = x @ W_qkv^T + bias, written directly into
// Q/K/V in (B,H,L,D) layout.  M=8192, N=3072, K=1024. 128x128 tile, 8x8 micro.
// ---------------------------------------------------------------------------
__global__ __launch_bounds__(256) void gemm_qkv_kernel(
    const float* __restrict__ X,     // (8192,1024)
    const float* __restrict__ W,     // (3072,1024)
    const float* __restrict__ qb,    // (1024)
    const float* __restrict__ vb,    // (1024)
    float* __restrict__ Q, float* __restrict__ K, float* __restrict__ V)
{
    __shared__ float aT[16][132];
    __shared__ float bT[16][132];
    const int tid = threadIdx.x;
    const int tx = tid & 15, ty = tid >> 4;
    const int m0 = blockIdx.x * 128;
    const int n0 = blockIdx.y * 128;

    float acc[8][8];
#pragma unroll
    for (int i = 0; i < 8; i++)
#pragma unroll
        for (int j = 0; j < 8; j++) acc[i][j] = 0.f;

    for (int k0 = 0; k0 < 1024; k0 += 16) {
#pragma unroll
        for (int i = 0; i < 2; i++) {
            int f   = i * 256 + tid;       // 0..511 float4 slots
            int row = f >> 2;              // 0..127
            int kq  = (f & 3) * 4;         // 0,4,8,12
            float4 av = *(const float4*)(X + (size_t)(m0 + row) * 1024 + k0 + kq);
            aT[kq + 0][row] = av.x; aT[kq + 1][row] = av.y;
            aT[kq + 2][row] = av.z; aT[kq + 3][row] = av.w;
            float4 bv = *(const float4*)(W + (size_t)(n0 + row) * 1024 + k0 + kq);
            bT[kq + 0][row] = bv.x; bT[kq + 1][row] = bv.y;
            bT[kq + 2][row] = bv.z; bT[kq + 3][row] = bv.w;
        }
        __syncthreads();
#pragma unroll
        for (int kk = 0; kk < 16; kk++) {
            float4 a0 = *(const float4*)&aT[kk][ty * 8];
            float4 a1 = *(const float4*)&aT[kk][ty * 8 + 4];
            float4 b0 = *(const float4*)&bT[kk][tx * 8];
            float4 b1 = *(const float4*)&bT[kk][tx * 8 + 4];
            float ar[8] = {a0.x, a0.y, a0.z, a0.w, a1.x, a1.y, a1.z, a1.w};
            float br[8] = {b0.x, b0.y, b0.z, b0.w, b1.x, b1.y, b1.z, b1.w};
#pragma unroll
            for (int i = 0; i < 8; i++)
#pragma unroll
                for (int j = 0; j < 8; j++)
                    acc[i][j] = fmaf(ar[i], br[j], acc[i][j]);
        }
        __syncthreads();
    }

    // Epilogue: bias + scatter into Q/K/V (B,H,L,D)
    // 'which' is uniform across the block (n0 block never crosses a 1024 boundary)
#pragma unroll
    for (int i = 0; i < 8; i++) {
        int m = m0 + ty * 8 + i;
        int b = m >> 10, l = m & 1023;
#pragma unroll
        for (int j = 0; j < 8; j++) {
            int n  = n0 + tx * 8 + j;
            int which = n >> 10;
            int hd = n & 1023;
            int h = hd >> 6, d = hd & 63;
            float v = acc[i][j];
            float* dst;
            if (which == 0)      { v += qb[hd]; dst = Q; }
            else if (which == 1) {              dst = K; }
            else                 { v += vb[hd]; dst = V; }
            dst[((size_t)(b * PH + h) * PL + l) * PD + d] = v;
        }
    }
}

// ---------------------------------------------------------------------------
// Kernel 2: fused l2norm (+scale for Q) + RoPE, in place on Q and K.
// One 64-lane wave per (b,h,l) row; 4 rows per block.
// ---------------------------------------------------------------------------
__global__ __launch_bounds__(256) void normrope_kernel(
    float* __restrict__ Q, float* __restrict__ K,
    const float* __restrict__ freqs,   // (1024,32,2)
    const float* __restrict__ sml)     // (16)
{
    int row  = blockIdx.x * 4 + (threadIdx.x >> 6);   // 0 .. 2*B*H*L-1
    int lane = threadIdx.x & 63;
    const int NROWS = PB * PH * PL;                   // 131072
    bool isQ = row < NROWS;
    int r = isQ ? row : row - NROWS;
    int h = (r >> 10) & (PH - 1);
    int l = r & (PL - 1);

    float* ptr = (isQ ? Q : K) + (size_t)r * PD + lane;
    float v = *ptr;
    float ss = v * v;
#pragma unroll
    for (int off = 32; off >= 1; off >>= 1) ss += __shfl_xor(ss, off);
    float n = fmaxf(sqrtf(ss), 1e-12f);
    float scale = 1.0f / n;
    if (isQ) scale *= __expf(fminf(sml[h], MAX_SCALE_MUL));
    v *= scale;

    // RoPE: pairs (2i, 2i+1)
    float partner = __shfl_xor(v, 1);
    int i = lane >> 1;
    float c = freqs[(l * 32 + i) * 2 + 0];
    float s = freqs[(l * 32 + i) * 2 + 1];
    float outv = (lane & 1) ? fmaf(partner, s, v * c)   // im = t0*s + t1*c
                            : fmaf(v, c, -partner * s); // re = t0*c - t1*s
    *ptr = outv;
}

// ---------------------------------------------------------------------------
// Kernel 3: flash attention.  64 Q-rows per block, iterate 16 K-tiles of 64.
// Online softmax; P goes through an LDS transpose for the PV matmul.
// ---------------------------------------------------------------------------
__global__ __launch_bounds__(256) void attn_kernel(
    const float* __restrict__ Q, const float* __restrict__ K,
    const float* __restrict__ V, const float* __restrict__ bias,
    float* __restrict__ O)
{
    __shared__ float qT[64][68];
    __shared__ float kT[64][68];
    __shared__ float vsm[64][68];
    __shared__ float PT[64][68];

    const int tid = threadIdx.x;
    const int tx = tid & 15, ty = tid >> 4;
    const int bh = blockIdx.y;                  // 0..127
    const int q0 = blockIdx.x * 64;
    const float* Qb = Q + (size_t)bh * PL * PD;
    const float* Kb = K + (size_t)bh * PL * PD;
    const float* Vb = V + (size_t)bh * PL * PD;

    // stage Q tile transposed: qT[d][r]
#pragma unroll
    for (int i = 0; i < 4; i++) {
        int f = i * 256 + tid;       // 0..1023
        int r = f >> 4;
        int dq = (f & 15) * 4;
        float4 v4 = *(const float4*)(Qb + (size_t)(q0 + r) * PD + dq);
        qT[dq + 0][r] = v4.x; qT[dq + 1][r] = v4.y;
        qT[dq + 2][r] = v4.z; qT[dq + 3][r] = v4.w;
    }

    const int r0 = ty * 4, d0 = tx * 4;
    float mi[4], li[4], acc[4][4];
#pragma unroll
    for (int i = 0; i < 4; i++) {
        mi[i] = -1e30f; li[i] = 0.f;
#pragma unroll
        for (int j = 0; j < 4; j++) acc[i][j] = 0.f;
    }

    for (int kb = 0; kb < 16; kb++) {
        // stage K (transposed) and V (row-major) tiles
#pragma unroll
        for (int i = 0; i < 4; i++) {
            int f = i * 256 + tid;
            int r = f >> 4;
            int dq = (f & 15) * 4;
            float4 kv = *(const float4*)(Kb + (size_t)(kb * 64 + r) * PD + dq);
            kT[dq + 0][r] = kv.x; kT[dq + 1][r] = kv.y;
            kT[dq + 2][r] = kv.z; kT[dq + 3][r] = kv.w;
            float4 vv = *(const float4*)(Vb + (size_t)(kb * 64 + r) * PD + dq);
            *(float4*)&vsm[r][dq] = vv;
        }
        __syncthreads();

        // S tile 4x4 per thread
        float s[4][4];
#pragma unroll
        for (int i = 0; i < 4; i++)
#pragma unroll
            for (int j = 0; j < 4; j++) s[i][j] = 0.f;
#pragma unroll 8
        for (int d = 0; d < 64; d++) {
            float4 qv = *(const float4*)&qT[d][r0];
            float4 kv = *(const float4*)&kT[d][tx * 4];
            float qa[4] = {qv.x, qv.y, qv.z, qv.w};
            float ka[4] = {kv.x, kv.y, kv.z, kv.w};
#pragma unroll
            for (int i = 0; i < 4; i++)
#pragma unroll
                for (int j = 0; j < 4; j++)
                    s[i][j] = fmaf(qa[i], ka[j], s[i][j]);
        }
        // + attn_bias
#pragma unroll
        for (int i = 0; i < 4; i++) {
            const float* brow = bias + (size_t)(q0 + r0 + i) * PL + kb * 64 + tx * 4;
#pragma unroll
            for (int j = 0; j < 4; j++) s[i][j] += brow[j];
        }

        // online softmax: row stats across the 16 tx-lanes of each ty-group
        float mt[4];
#pragma unroll
        for (int i = 0; i < 4; i++)
            mt[i] = fmaxf(fmaxf(s[i][0], s[i][1]), fmaxf(s[i][2], s[i][3]));
#pragma unroll
        for (int off = 1; off < 16; off <<= 1)
#pragma unroll
            for (int i = 0; i < 4; i++) mt[i] = fmaxf(mt[i], __shfl_xor(mt[i], off));

        float rs[4];
#pragma unroll
        for (int i = 0; i < 4; i++) {
            float nm = fmaxf(mi[i], mt[i]);
            float al = __expf(mi[i] - nm);
            mi[i] = nm;
            float sum = 0.f;
#pragma unroll
            for (int j = 0; j < 4; j++) {
                float p = __expf(s[i][j] - nm);
                s[i][j] = p;
                sum += p;
            }
            rs[i] = sum;
            li[i] *= al;
#pragma unroll
            for (int j = 0; j < 4; j++) acc[i][j] *= al;
        }
#pragma unroll
        for (int off = 1; off < 16; off <<= 1)
#pragma unroll
            for (int i = 0; i < 4; i++) rs[i] += __shfl_xor(rs[i], off);
#pragma unroll
        for (int i = 0; i < 4; i++) li[i] += rs[i];

        // P -> LDS transposed: PT[c][r]
#pragma unroll
        for (int i = 0; i < 4; i++)
#pragma unroll
            for (int j = 0; j < 4; j++) PT[tx * 4 + j][r0 + i] = s[i][j];
        __syncthreads();

        // O += P @ V
#pragma unroll 8
        for (int c = 0; c < 64; c++) {
            float4 pv = *(const float4*)&PT[c][r0];
            float4 vv = *(const float4*)&vsm[c][d0];
            float pa[4] = {pv.x, pv.y, pv.z, pv.w};
            float va[4] = {vv.x, vv.y, vv.z, vv.w};
#pragma unroll
            for (int i = 0; i < 4; i++)
#pragma unroll
                for (int j = 0; j < 4; j++)
                    acc[i][j] = fmaf(pa[i], va[j], acc[i][j]);
        }
        __syncthreads();
    }

    // finalize
#pragma unroll
    for (int i = 0; i < 4; i++) {
        float inv = 1.0f / li[i];
        float4 o = make_float4(acc[i][0] * inv, acc[i][1] * inv,
                               acc[i][2] * inv, acc[i][3] * inv);
        *(float4*)(O + (size_t)(bh * PL + q0 + r0 + i) * PD + d0) = o;
    }
}

// ---------------------------------------------------------------------------
// Kernel 4: out-proj GEMM.  out = gather(attn_out) @ W_proj^T + b_proj.
// A[m][k] = AT[((b*16+h)*1024+l)*64+d], m=b*1024+l, k=h*64+d.
// ---------------------------------------------------------------------------
__global__ __launch_bounds__(256) void gemm_proj_kernel(
    const float* __restrict__ A,     // attn_out (B,H,L,D)
    const float* __restrict__ W,     // (1024,1024)
    const float* __restrict__ bp,    // (1024)
    float* __restrict__ Out)         // (8192,1024)
{
    __shared__ float aT[16][132];
    __shared__ float bT[16][132];
    const int tid = threadIdx.x;
    const int tx = tid & 15, ty = tid >> 4;
    const int m0 = blockIdx.x * 128;
    const int n0 = blockIdx.y * 128;

    float acc[8][8];
#pragma unroll
    for (int i = 0; i < 8; i++)
#pragma unroll
        for (int j = 0; j < 8; j++) acc[i][j] = 0.f;

    for (int k0 = 0; k0 < 1024; k0 += 16) {
#pragma unroll
        for (int i = 0; i < 2; i++) {
            int f   = i * 256 + tid;
            int row = f >> 2;
            int kq  = (f & 3) * 4;
            int m = m0 + row;
            int b = m >> 10, l = m & 1023;
            int k = k0 + kq;
            int h = k >> 6, d = k & 63;
            float4 av = *(const float4*)(A + ((size_t)(b * PH + h) * PL + l) * PD + d);
            aT[kq + 0][row] = av.x; aT[kq + 1][row] = av.y;
            aT[kq + 2][row] = av.z; aT[kq + 3][row] = av.w;
            float4 bv = *(const float4*)(W + (size_t)(n0 + row) * 1024 + k0 + kq);
            bT[kq + 0][row] = bv.x; bT[kq + 1][row] = bv.y;
            bT[kq + 2][row] = bv.z; bT[kq + 3][row] = bv.w;
        }
        __syncthreads();
#pragma unroll
        for (int kk = 0; kk < 16; kk++) {
            float4 a0 = *(const float4*)&aT[kk][ty * 8];
            float4 a1 = *(const float4*)&aT[kk][ty * 8 + 4];
            float4 b0 = *(const float4*)&bT[kk][tx * 8];
            float4 b1 = *(const float4*)&bT[kk][tx * 8 + 4];
            float ar[8] = {a0.x, a0.y, a0.z, a0.w, a1.x, a1.y, a1.z, a1.w};
            float br[8] = {b0.x, b0.y, b0.z, b0.w, b1.x, b1.y, b1.z, b1.w};
#pragma unroll
            for (int i = 0; i < 8; i++)
#pragma unroll
                for (int j = 0; j < 8; j++)
                    acc[i][j] = fmaf(ar[i], br[j], acc[i][j]);
        }
        __syncthreads();
    }

#pragma unroll
    for (int i = 0; i < 8; i++) {
        int m = m0 + ty * 8 + i;
        float* orow = Out + (size_t)m * 1024 + n0 + tx * 8;
        float4 o0 = make_float4(acc[i][0] + bp[n0 + tx * 8 + 0],
                                acc[i][1] + bp[n0 + tx * 8 + 1],
                                acc[i][2] + bp[n0 + tx * 8 + 2],
                                acc[i][3] + bp[n0 + tx * 8 + 3]);
        float4 o1 = make_float4(acc[i][4] + bp[n0 + tx * 8 + 4],
                                acc[i][5] + bp[n0 + tx * 8 + 5],
                                acc[i][6] + bp[n0 + tx * 8 + 6],
                                acc[i][7] + bp[n0 + tx * 8 + 7]);
        *(float4*)orow = o0;
        *(float4*)(orow + 4) = o1;
    }
}

// ---------------------------------------------------------------------------
extern "C" void kernel_launch(void* const* d_in, const int* in_sizes, int n_in,
                              void* d_out, int out_size, void* d_ws, size_t ws_size,
                              hipStream_t stream)
{
    const float* x         = (const float*)d_in[0];
    const float* freqs     = (const float*)d_in[1];
    const float* attn_bias = (const float*)d_in[2];
    const float* W_qkv     = (const float*)d_in[3];
    const float* q_bias    = (const float*)d_in[4];
    const float* v_bias    = (const float*)d_in[5];
    const float* sml       = (const float*)d_in[6];
    const float* W_proj    = (const float*)d_in[7];
    const float* b_proj    = (const float*)d_in[8];
    float* out = (float*)d_out;

    const size_t NE = (size_t)PB * PH * PL * PD;   // 8,388,608 elements
    float* Q  = (float*)d_ws;
    float* K  = Q + NE;
    float* V  = K + NE;
    float* AT = V + NE;

    // 1. QKV projection
    gemm_qkv_kernel<<<dim3(64, 24), 256, 0, stream>>>(x, W_qkv, q_bias, v_bias, Q, K, V);
    // 2. l2norm + scale + RoPE (in place on Q, K)
    normrope_kernel<<<dim3(65536), 256, 0, stream>>>(Q, K, freqs, sml);
    // 3. flash attention
    attn_kernel<<<dim3(16, 128), 256, 0, stream>>>(Q, K, V, attn_bias, AT);
    // 4. output projection
    gemm_proj_kernel<<<dim3(64, 8), 256, 0, stream>>>(AT, W_proj, b_proj, out);
}

// Round 2
// 433.063 us; speedup vs baseline: 3.4932x; 3.4932x over previous
//
#include <hip/hip_runtime.h>
#include <math.h>

#define PB 8
#define PL 1024
#define PC 1024
#define PH 16
#define PD 64
#define MAX_SCALE_MUL 4.605170185988092f  // log(100)

typedef __attribute__((ext_vector_type(8))) short s16x8;
typedef __attribute__((ext_vector_type(4))) float f32x4;

#define MFMA16(a, b, c) __builtin_amdgcn_mfma_f32_16x16x32_bf16(a, b, c, 0, 0, 0)

// fp32 -> bf16 round-to-nearest-even
__device__ __forceinline__ unsigned short f2bf(float f) {
    unsigned u = __float_as_uint(f);
    unsigned r = (u + 0x7fffu + ((u >> 16) & 1u)) >> 16;
    return (unsigned short)r;
}

// async global->LDS, 16 bytes per lane; lptr must be wave-uniform
__device__ __forceinline__ void gl2lds16(const void* g, void* l) {
    __builtin_amdgcn_global_load_lds(
        (const __attribute__((address_space(1))) unsigned int*)g,
        (__attribute__((address_space(3))) unsigned int*)l, 16, 0, 0);
}

// ---------------------------------------------------------------------------
// cast fp32 -> bf16, 4 elems/thread (n must be multiple of 1024)
// ---------------------------------------------------------------------------
__global__ __launch_bounds__(256) void cast_bf16_kernel(
    const float* __restrict__ in, unsigned short* __restrict__ out)
{
    int i = blockIdx.x * 256 + threadIdx.x;
    float4 v = ((const float4*)in)[i];
    unsigned a = (unsigned)f2bf(v.x) | ((unsigned)f2bf(v.y) << 16);
    unsigned b = (unsigned)f2bf(v.z) | ((unsigned)f2bf(v.w) << 16);
    ((uint2*)out)[i] = make_uint2(a, b);
}

// ---------------------------------------------------------------------------
// Kernel 1: QKV GEMM (bf16 MFMA).  C = Xh(8192x1024) . Wh(3072x1024)^T
// 128x128 tile, BK=32, 4 waves in 2x2, each wave 4x4 16x16 frags.
// LDS staged via global_load_lds(16B) with XOR chunk swizzle (2-way max).
// Epilogue scatters Q,K fp32 and V bf16 into (B,H,L,D) with biases.
// ---------------------------------------------------------------------------
__global__ __launch_bounds__(256) void gemm_qkv_mfma(
    const unsigned short* __restrict__ Xh,
    const unsigned short* __restrict__ Wh,
    const float* __restrict__ qb, const float* __restrict__ vb,
    float* __restrict__ Qf, float* __restrict__ Kf,
    unsigned short* __restrict__ Vh)
{
    __shared__ unsigned short As[128 * 32];
    __shared__ unsigned short Bs[128 * 32];
    const int tid  = threadIdx.x;
    const int wave = tid >> 6, lane = tid & 63;
    const int wm = wave & 1, wn = wave >> 1;
    const int quad = lane >> 4, rr = lane & 15;
    const int m0 = blockIdx.x * 128, n0 = blockIdx.y * 128;

    f32x4 acc[4][4];
#pragma unroll
    for (int i = 0; i < 4; i++)
#pragma unroll
        for (int j = 0; j < 4; j++) acc[i][j] = (f32x4){0.f, 0.f, 0.f, 0.f};

    // staging: wave stages rows [wave*32, wave*32+32) of A and B, 2 instrs each
    const int rw = lane >> 2;                    // 0..15 row within instr
    const int cc = lane & 3;                     // chunk 0..3
    const int g  = cc ^ ((rw >> 1) & 3);         // swizzled global chunk
    const int srow = wave * 32 + rw;
    const unsigned short* gA0 = Xh + (size_t)(m0 + srow) * 1024 + g * 8;
    const unsigned short* gA1 = gA0 + (size_t)16 * 1024;
    const unsigned short* gB0 = Wh + (size_t)(n0 + srow) * 1024 + g * 8;
    const unsigned short* gB1 = gB0 + (size_t)16 * 1024;
    unsigned short* lA0 = &As[(wave * 32) * 32];
    unsigned short* lA1 = &As[(wave * 32 + 16) * 32];
    unsigned short* lB0 = &Bs[(wave * 32) * 32];
    unsigned short* lB1 = &Bs[(wave * 32 + 16) * 32];

    const int swz = (rr >> 1) & 3;               // read-side swizzle
    const int coff = ((quad ^ swz) * 8);

    for (int k0 = 0; k0 < 1024; k0 += 32) {
        gl2lds16(gA0, lA0); gl2lds16(gA1, lA1);
        gl2lds16(gB0, lB0); gl2lds16(gB1, lB1);
        gA0 += 32; gA1 += 32; gB0 += 32; gB1 += 32;
        __syncthreads();

        s16x8 af[4], bf[4];
#pragma unroll
        for (int i = 0; i < 4; i++)
            af[i] = *(const s16x8*)&As[(wm * 64 + i * 16 + rr) * 32 + coff];
#pragma unroll
        for (int j = 0; j < 4; j++)
            bf[j] = *(const s16x8*)&Bs[(wn * 64 + j * 16 + rr) * 32 + coff];
#pragma unroll
        for (int i = 0; i < 4; i++)
#pragma unroll
            for (int j = 0; j < 4; j++)
                acc[i][j] = MFMA16(af[i], bf[j], acc[i][j]);
        __syncthreads();
    }

    // epilogue: C row = m0+wm*64+i*16+quad*4+reg ; col = n0+wn*64+j*16+rr
    const int b = m0 >> 10;
    const int which = n0 >> 10;                 // uniform: 0=Q 1=K 2=V
    const int hbase = ((n0 & 1023) + wn * 64) >> 6;   // head (uniform per wave)
#pragma unroll
    for (int j = 0; j < 4; j++) {
        const int d  = j * 16 + rr;
        const int hd = hbase * 64 + d;
        const size_t obase = ((size_t)(b * PH + hbase) * PL) * PD + d;
        float bias = 0.f;
        if (which == 0) bias = qb[hd];
        if (which == 2) bias = vb[hd];
#pragma unroll
        for (int i = 0; i < 4; i++) {
            const int lb = (m0 & 1023) + wm * 64 + i * 16 + quad * 4;
#pragma unroll
            for (int reg = 0; reg < 4; reg++) {
                float v = acc[i][j][reg] + bias;
                size_t idx = obase + (size_t)(lb + reg) * PD;
                if (which == 0)      Qf[idx] = v;
                else if (which == 1) Kf[idx] = v;
                else                 Vh[idx] = f2bf(v);
            }
        }
    }
}

// ---------------------------------------------------------------------------
// Kernel 2: l2norm (+scale for Q) + RoPE; fp32 in, bf16 out. 1 wave/row.
// ---------------------------------------------------------------------------
__global__ __launch_bounds__(256) void normrope_kernel(
    const float* __restrict__ Qf, const float* __restrict__ Kf,
    unsigned short* __restrict__ Qh, unsigned short* __restrict__ Kh,
    const float* __restrict__ freqs, const float* __restrict__ sml)
{
    int row  = blockIdx.x * 4 + (threadIdx.x >> 6);
    int lane = threadIdx.x & 63;
    const int NROWS = PB * PH * PL;
    bool isQ = row < NROWS;
    int r = isQ ? row : row - NROWS;
    int h = (r >> 10) & (PH - 1);
    int l = r & (PL - 1);

    float v = (isQ ? Qf : Kf)[(size_t)r * PD + lane];
    float ss = v * v;
#pragma unroll
    for (int off = 32; off >= 1; off >>= 1) ss += __shfl_xor(ss, off);
    float scale = 1.0f / fmaxf(sqrtf(ss), 1e-12f);
    if (isQ) scale *= __expf(fminf(sml[h], MAX_SCALE_MUL));
    v *= scale;

    float partner = __shfl_xor(v, 1);
    int i = lane >> 1;
    float c = freqs[(l * 32 + i) * 2 + 0];
    float s = freqs[(l * 32 + i) * 2 + 1];
    float outv = (lane & 1) ? fmaf(partner, s, v * c)
                            : fmaf(v, c, -partner * s);
    (isQ ? Qh : Kh)[(size_t)r * PD + lane] = f2bf(outv);
}

// ---------------------------------------------------------------------------
// Kernel 3: transpose V (B,H,L,D) -> Vt (B,H,D,L), bf16. Gather reads, packed
// coalesced writes; reads are line-shared within the block (L1/L2 hits).
// ---------------------------------------------------------------------------
__global__ __launch_bounds__(256) void transpose_v_kernel(
    const unsigned short* __restrict__ Vh, unsigned short* __restrict__ Vt)
{
    int bh = blockIdx.x >> 4;
    int l0 = (blockIdx.x & 15) * 64;
    int tid = threadIdx.x;
#pragma unroll
    for (int s = 0; s < 2; s++) {
        int slot = s * 256 + tid;          // 0..511
        int d  = slot & 63;
        int lb = l0 + (slot >> 6) * 8;     // 8 l's per chunk
        unsigned o[4];
#pragma unroll
        for (int i = 0; i < 4; i++) {
            unsigned short a0 = Vh[((size_t)bh * PL + lb + 2 * i) * PD + d];
            unsigned short a1 = Vh[((size_t)bh * PL + lb + 2 * i + 1) * PD + d];
            o[i] = (unsigned)a0 | ((unsigned)a1 << 16);
        }
        *(uint4*)&Vt[((size_t)bh * PD + d) * PL + lb] = make_uint4(o[0], o[1], o[2], o[3]);
    }
}

// ---------------------------------------------------------------------------
// Kernel 4: flash attention, bf16 MFMA. Block = 64 Q-rows x one (b,h).
// Wave w owns Q-rows w*16..w*16+15. K-tiles of 64 keys; online softmax.
// Tiles staged via global_load_lds with XOR row-chunk swizzle.
// Output written bf16 in (B,L,H,D) layout for the proj GEMM.
// ---------------------------------------------------------------------------
__global__ __launch_bounds__(256) void attn_mfma(
    const unsigned short* __restrict__ Qh, const unsigned short* __restrict__ Kh,
    const unsigned short* __restrict__ Vt, const float* __restrict__ bias,
    unsigned short* __restrict__ O)
{
    __shared__ unsigned short Qs[64 * 64];
    __shared__ unsigned short Ks[64 * 64];
    __shared__ unsigned short Vs[64 * 64];
    __shared__ unsigned short Ps[4][16 * 72];   // per-wave P, stride 72 (144B)

    const int tid  = threadIdx.x;
    const int wave = tid >> 6, lane = tid & 63;
    const int quad = lane >> 4, rr = lane & 15;
    const int bh = blockIdx.y, q0 = blockIdx.x * 64;
    const int b = bh >> 4, h = bh & 15;

    // staging geometry: wave stages rows [wave*16, wave*16+16), 2 instrs
    const int sr = wave * 16 + (lane >> 3);     // row of t=0 instr
    const int sc = lane & 7;
    const int sg = sc ^ (sr & 7);               // swizzled global chunk

    // stage Q once
    gl2lds16(Qh + ((size_t)bh * PL + q0 + sr) * PD + sg * 8, &Qs[(wave * 16) * 64]);
    gl2lds16(Qh + ((size_t)bh * PL + q0 + sr + 8) * PD + sg * 8, &Qs[(wave * 16 + 8) * 64]);
    __syncthreads();

    const int swz8 = rr & 7;
    s16x8 qA[2];
#pragma unroll
    for (int kk = 0; kk < 2; kk++)
        qA[kk] = *(const s16x8*)&Qs[(wave * 16 + rr) * 64 + ((kk * 4 + quad) ^ swz8) * 8];

    f32x4 accO[4];
    float mrow[4], lrow[4];
#pragma unroll
    for (int jd = 0; jd < 4; jd++) accO[jd] = (f32x4){0.f, 0.f, 0.f, 0.f};
#pragma unroll
    for (int reg = 0; reg < 4; reg++) { mrow[reg] = -3.0e38f; lrow[reg] = 0.f; }

    __syncthreads();  // Qs frag reads done before Ks/Vs staging reuses nothing, but keep waves aligned

    for (int kb = 0; kb < 16; kb++) {
        gl2lds16(Kh + ((size_t)bh * PL + kb * 64 + sr) * PD + sg * 8, &Ks[(wave * 16) * 64]);
        gl2lds16(Kh + ((size_t)bh * PL + kb * 64 + sr + 8) * PD + sg * 8, &Ks[(wave * 16 + 8) * 64]);
        gl2lds16(Vt + ((size_t)bh * PD + sr) * PL + kb * 64 + sg * 8, &Vs[(wave * 16) * 64]);
        gl2lds16(Vt + ((size_t)bh * PD + sr + 8) * PL + kb * 64 + sg * 8, &Vs[(wave * 16 + 8) * 64]);
        __syncthreads();

        // S = Q.K^T for 4 key sub-tiles
        f32x4 sc4[4];
#pragma unroll
        for (int j = 0; j < 4; j++) {
            s16x8 kB0 = *(const s16x8*)&Ks[(j * 16 + rr) * 64 + ((0 + quad) ^ swz8) * 8];
            s16x8 kB1 = *(const s16x8*)&Ks[(j * 16 + rr) * 64 + ((4 + quad) ^ swz8) * 8];
            f32x4 z = (f32x4){0.f, 0.f, 0.f, 0.f};
            z = MFMA16(qA[0], kB0, z);
            z = MFMA16(qA[1], kB1, z);
            sc4[j] = z;
        }
        // + attn_bias  (row = q0+wave*16+quad*4+reg, col = kb*64+j*16+rr)
#pragma unroll
        for (int reg = 0; reg < 4; reg++) {
            const float* brow = bias + (size_t)(q0 + wave * 16 + quad * 4 + reg) * PL + kb * 64 + rr;
#pragma unroll
            for (int j = 0; j < 4; j++) sc4[j][reg] += brow[j * 16];
        }

        // online softmax (rows live in lanes of same quad; reduce over low 4 bits)
        float mt[4];
#pragma unroll
        for (int reg = 0; reg < 4; reg++)
            mt[reg] = fmaxf(fmaxf(sc4[0][reg], sc4[1][reg]), fmaxf(sc4[2][reg], sc4[3][reg]));
#pragma unroll
        for (int off = 1; off < 16; off <<= 1)
#pragma unroll
            for (int reg = 0; reg < 4; reg++) mt[reg] = fmaxf(mt[reg], __shfl_xor(mt[reg], off));

        float al[4], rs[4];
#pragma unroll
        for (int reg = 0; reg < 4; reg++) {
            float mn = fmaxf(mrow[reg], mt[reg]);
            al[reg] = __expf(mrow[reg] - mn);
            mrow[reg] = mn;
        }
#pragma unroll
        for (int reg = 0; reg < 4; reg++) {
            float sum = 0.f;
#pragma unroll
            for (int j = 0; j < 4; j++) {
                float p = __expf(sc4[j][reg] - mrow[reg]);
                sc4[j][reg] = p;
                sum += p;
            }
            rs[reg] = sum;
        }
#pragma unroll
        for (int off = 1; off < 16; off <<= 1)
#pragma unroll
            for (int reg = 0; reg < 4; reg++) rs[reg] += __shfl_xor(rs[reg], off);
#pragma unroll
        for (int reg = 0; reg < 4; reg++) lrow[reg] = lrow[reg] * al[reg] + rs[reg];
#pragma unroll
        for (int jd = 0; jd < 4; jd++)
#pragma unroll
            for (int reg = 0; reg < 4; reg++) accO[jd][reg] *= al[reg];

        // P -> wave-private LDS (C-layout -> A-layout transpose)
#pragma unroll
        for (int j = 0; j < 4; j++)
#pragma unroll
            for (int reg = 0; reg < 4; reg++)
                Ps[wave][(quad * 4 + reg) * 72 + j * 16 + rr] = f2bf(sc4[j][reg]);
        // same-wave LDS ops are in-order: no barrier needed
        s16x8 pA0 = *(const s16x8*)&Ps[wave][rr * 72 + quad * 8];
        s16x8 pA1 = *(const s16x8*)&Ps[wave][rr * 72 + 32 + quad * 8];

        // O += P.V  (B-frag: n=d from Vs rows, k=key contiguous)
#pragma unroll
        for (int jd = 0; jd < 4; jd++) {
            s16x8 vB0 = *(const s16x8*)&Vs[(jd * 16 + rr) * 64 + ((0 + quad) ^ swz8) * 8];
            s16x8 vB1 = *(const s16x8*)&Vs[(jd * 16 + rr) * 64 + ((4 + quad) ^ swz8) * 8];
            accO[jd] = MFMA16(pA0, vB0, accO[jd]);
            accO[jd] = MFMA16(pA1, vB1, accO[jd]);
        }
        __syncthreads();
    }

    // epilogue: divide by l, store bf16 to (B,L,H,D)
#pragma unroll
    for (int reg = 0; reg < 4; reg++) {
        float inv = 1.0f / lrow[reg];
        int l = q0 + wave * 16 + quad * 4 + reg;
        size_t base = ((size_t)(b * PL + l) * PH + h) * PD + rr;
#pragma unroll
        for (int jd = 0; jd < 4; jd++)
            O[base + jd * 16] = f2bf(accO[jd][reg] * inv);
    }
}

// ---------------------------------------------------------------------------
// Kernel 5: out-proj GEMM (bf16 MFMA). Out = Oh(8192x1024).Wph(1024x1024)^T + bp
// ---------------------------------------------------------------------------
__global__ __launch_bounds__(256) void gemm_proj_mfma(
    const unsigned short* __restrict__ Ah,
    const unsigned short* __restrict__ Wh,
    const float* __restrict__ bp, float* __restrict__ Out)
{
    __shared__ unsigned short As[128 * 32];
    __shared__ unsigned short Bs[128 * 32];
    const int tid  = threadIdx.x;
    const int wave = tid >> 6, lane = tid & 63;
    const int wm = wave & 1, wn = wave >> 1;
    const int quad = lane >> 4, rr = lane & 15;
    const int m0 = blockIdx.x * 128, n0 = blockIdx.y * 128;

    f32x4 acc[4][4];
#pragma unroll
    for (int i = 0; i < 4; i++)
#pragma unroll
        for (int j = 0; j < 4; j++) acc[i][j] = (f32x4){0.f, 0.f, 0.f, 0.f};

    const int rw = lane >> 2;
    const int cc = lane & 3;
    const int g  = cc ^ ((rw >> 1) & 3);
    const int srow = wave * 32 + rw;
    const unsigned short* gA0 = Ah + (size_t)(m0 + srow) * 1024 + g * 8;
    const unsigned short* gA1 = gA0 + (size_t)16 * 1024;
    const unsigned short* gB0 = Wh + (size_t)(n0 + srow) * 1024 + g * 8;
    const unsigned short* gB1 = gB0 + (size_t)16 * 1024;
    unsigned short* lA0 = &As[(wave * 32) * 32];
    unsigned short* lA1 = &As[(wave * 32 + 16) * 32];
    unsigned short* lB0 = &Bs[(wave * 32) * 32];
    unsigned short* lB1 = &Bs[(wave * 32 + 16) * 32];

    const int swz = (rr >> 1) & 3;
    const int coff = ((quad ^ swz) * 8);

    for (int k0 = 0; k0 < 1024; k0 += 32) {
        gl2lds16(gA0, lA0); gl2lds16(gA1, lA1);
        gl2lds16(gB0, lB0); gl2lds16(gB1, lB1);
        gA0 += 32; gA1 += 32; gB0 += 32; gB1 += 32;
        __syncthreads();

        s16x8 af[4], bf[4];
#pragma unroll
        for (int i = 0; i < 4; i++)
            af[i] = *(const s16x8*)&As[(wm * 64 + i * 16 + rr) * 32 + coff];
#pragma unroll
        for (int j = 0; j < 4; j++)
            bf[j] = *(const s16x8*)&Bs[(wn * 64 + j * 16 + rr) * 32 + coff];
#pragma unroll
        for (int i = 0; i < 4; i++)
#pragma unroll
            for (int j = 0; j < 4; j++)
                acc[i][j] = MFMA16(af[i], bf[j], acc[i][j]);
        __syncthreads();
    }

#pragma unroll
    for (int i = 0; i < 4; i++) {
        const int mb = m0 + wm * 64 + i * 16 + quad * 4;
#pragma unroll
        for (int j = 0; j < 4; j++) {
            const int n = n0 + wn * 64 + j * 16 + rr;
            const float bb = bp[n];
#pragma unroll
            for (int reg = 0; reg < 4; reg++)
                Out[(size_t)(mb + reg) * 1024 + n] = acc[i][j][reg] + bb;
        }
    }
}

// ---------------------------------------------------------------------------
extern "C" void kernel_launch(void* const* d_in, const int* in_sizes, int n_in,
                              void* d_out, int out_size, void* d_ws, size_t ws_size,
                              hipStream_t stream)
{
    const float* x         = (const float*)d_in[0];
    const float* freqs     = (const float*)d_in[1];
    const float* attn_bias = (const float*)d_in[2];
    const float* W_qkv     = (const float*)d_in[3];
    const float* q_bias    = (const float*)d_in[4];
    const float* v_bias    = (const float*)d_in[5];
    const float* sml       = (const float*)d_in[6];
    const float* W_proj    = (const float*)d_in[7];
    const float* b_proj    = (const float*)d_in[8];
    float* out = (float*)d_out;

    unsigned char* w = (unsigned char*)d_ws;
    const size_t MB = 1ull << 20;
    // layout (120 MiB total; round-0 proved >=128 MiB available):
    unsigned short* xh  = (unsigned short*)(w + 0);        // 16 MiB, dead after qkv
    unsigned short* wqh = (unsigned short*)(w + 16 * MB);  //  6 MiB, dead after qkv
    unsigned short* wph = (unsigned short*)(w + 22 * MB);  //  2 MiB, live till proj
    float*          Qf  = (float*)(w + 24 * MB);           // 32 MiB, dead after normrope
    float*          Kf  = (float*)(w + 56 * MB);           // 32 MiB, dead after normrope
    unsigned short* Vh  = (unsigned short*)(w + 88 * MB);  // 16 MiB, dead after transpose
    unsigned short* Qh  = (unsigned short*)(w + 0);        // overlays xh
    unsigned short* Kh  = (unsigned short*)(w + 104 * MB); // 16 MiB
    unsigned short* Vt  = (unsigned short*)(w + 24 * MB);  // overlays Qf[0:16M]
    unsigned short* Oh  = (unsigned short*)(w + 40 * MB);  // overlays Qf[16M:32M]

    // casts
    cast_bf16_kernel<<<8192, 256, 0, stream>>>(x, xh);
    cast_bf16_kernel<<<3072, 256, 0, stream>>>(W_qkv, wqh);
    cast_bf16_kernel<<<1024, 256, 0, stream>>>(W_proj, wph);
    // 1. QKV projection (MFMA)
    gemm_qkv_mfma<<<dim3(64, 24), 256, 0, stream>>>(xh, wqh, q_bias, v_bias, Qf, Kf, Vh);
    // 2. l2norm + scale + RoPE -> bf16
    normrope_kernel<<<65536, 256, 0, stream>>>(Qf, Kf, Qh, Kh, freqs, sml);
    // 3. V transpose (B,H,L,D) -> (B,H,D,L)
    transpose_v_kernel<<<2048, 256, 0, stream>>>(Vh, Vt);
    // 4. flash attention (MFMA)
    attn_mfma<<<dim3(16, 128), 256, 0, stream>>>(Qh, Kh, Vt, attn_bias, Oh);
    // 5. output projection (MFMA)
    gemm_proj_mfma<<<dim3(64, 8), 256, 0, stream>>>(Oh, wph, b_proj, out);
}

// Round 3
// 349.816 us; speedup vs baseline: 4.3245x; 1.2380x over previous
//
#include <hip/hip_runtime.h>
#include <math.h>

#define PB 8
#define PL 1024
#define PC 1024
#define PH 16
#define PD 64
#define MAX_SCALE_MUL 4.605170185988092f  // log(100)

typedef __attribute__((ext_vector_type(8))) short s16x8;
typedef __attribute__((ext_vector_type(4))) float f32x4;

#define MFMA16(a, b, c) __builtin_amdgcn_mfma_f32_16x16x32_bf16(a, b, c, 0, 0, 0)

// fp32 -> bf16 round-to-nearest-even
__device__ __forceinline__ unsigned short f2bf(float f) {
    unsigned u = __float_as_uint(f);
    unsigned r = (u + 0x7fffu + ((u >> 16) & 1u)) >> 16;
    return (unsigned short)r;
}

// async global->LDS, 16 bytes per lane; lptr must be wave-uniform
__device__ __forceinline__ void gl2lds16(const void* g, void* l) {
    __builtin_amdgcn_global_load_lds(
        (const __attribute__((address_space(1))) unsigned int*)g,
        (__attribute__((address_space(3))) unsigned int*)l, 16, 0, 0);
}

// ---------------------------------------------------------------------------
// cast fp32 -> bf16, 4 elems/thread (n must be multiple of 1024)
// ---------------------------------------------------------------------------
__global__ __launch_bounds__(256) void cast_bf16_kernel(
    const float* __restrict__ in, unsigned short* __restrict__ out)
{
    int i = blockIdx.x * 256 + threadIdx.x;
    float4 v = ((const float4*)in)[i];
    unsigned a = (unsigned)f2bf(v.x) | ((unsigned)f2bf(v.y) << 16);
    unsigned b = (unsigned)f2bf(v.z) | ((unsigned)f2bf(v.w) << 16);
    ((uint2*)out)[i] = make_uint2(a, b);
}

// ---------------------------------------------------------------------------
// Kernel 1: QKV GEMM (bf16 MFMA).  C = Xh(8192x1024) . Wh(3072x1024)^T
// 128x128 tile, BK=32, 4 waves in 2x2, each wave 4x4 16x16 frags.
// ---------------------------------------------------------------------------
__global__ __launch_bounds__(256) void gemm_qkv_mfma(
    const unsigned short* __restrict__ Xh,
    const unsigned short* __restrict__ Wh,
    const float* __restrict__ qb, const float* __restrict__ vb,
    float* __restrict__ Qf, float* __restrict__ Kf,
    unsigned short* __restrict__ Vh)
{
    __shared__ unsigned short As[128 * 32];
    __shared__ unsigned short Bs[128 * 32];
    const int tid  = threadIdx.x;
    const int wave = tid >> 6, lane = tid & 63;
    const int wm = wave & 1, wn = wave >> 1;
    const int quad = lane >> 4, rr = lane & 15;
    const int m0 = blockIdx.x * 128, n0 = blockIdx.y * 128;

    f32x4 acc[4][4];
#pragma unroll
    for (int i = 0; i < 4; i++)
#pragma unroll
        for (int j = 0; j < 4; j++) acc[i][j] = (f32x4){0.f, 0.f, 0.f, 0.f};

    const int rw = lane >> 2;
    const int cc = lane & 3;
    const int g  = cc ^ ((rw >> 1) & 3);
    const int srow = wave * 32 + rw;
    const unsigned short* gA0 = Xh + (size_t)(m0 + srow) * 1024 + g * 8;
    const unsigned short* gA1 = gA0 + (size_t)16 * 1024;
    const unsigned short* gB0 = Wh + (size_t)(n0 + srow) * 1024 + g * 8;
    const unsigned short* gB1 = gB0 + (size_t)16 * 1024;
    unsigned short* lA0 = &As[(wave * 32) * 32];
    unsigned short* lA1 = &As[(wave * 32 + 16) * 32];
    unsigned short* lB0 = &Bs[(wave * 32) * 32];
    unsigned short* lB1 = &Bs[(wave * 32 + 16) * 32];

    const int swz = (rr >> 1) & 3;
    const int coff = ((quad ^ swz) * 8);

    for (int k0 = 0; k0 < 1024; k0 += 32) {
        gl2lds16(gA0, lA0); gl2lds16(gA1, lA1);
        gl2lds16(gB0, lB0); gl2lds16(gB1, lB1);
        gA0 += 32; gA1 += 32; gB0 += 32; gB1 += 32;
        __syncthreads();

        s16x8 af[4], bf[4];
#pragma unroll
        for (int i = 0; i < 4; i++)
            af[i] = *(const s16x8*)&As[(wm * 64 + i * 16 + rr) * 32 + coff];
#pragma unroll
        for (int j = 0; j < 4; j++)
            bf[j] = *(const s16x8*)&Bs[(wn * 64 + j * 16 + rr) * 32 + coff];
#pragma unroll
        for (int i = 0; i < 4; i++)
#pragma unroll
            for (int j = 0; j < 4; j++)
                acc[i][j] = MFMA16(af[i], bf[j], acc[i][j]);
        __syncthreads();
    }

    const int b = m0 >> 10;
    const int which = n0 >> 10;                 // uniform: 0=Q 1=K 2=V
    const int hbase = ((n0 & 1023) + wn * 64) >> 6;
#pragma unroll
    for (int j = 0; j < 4; j++) {
        const int d  = j * 16 + rr;
        const int hd = hbase * 64 + d;
        const size_t obase = ((size_t)(b * PH + hbase) * PL) * PD + d;
        float bias = 0.f;
        if (which == 0) bias = qb[hd];
        if (which == 2) bias = vb[hd];
#pragma unroll
        for (int i = 0; i < 4; i++) {
            const int lb = (m0 & 1023) + wm * 64 + i * 16 + quad * 4;
#pragma unroll
            for (int reg = 0; reg < 4; reg++) {
                float v = acc[i][j][reg] + bias;
                size_t idx = obase + (size_t)(lb + reg) * PD;
                if (which == 0)      Qf[idx] = v;
                else if (which == 1) Kf[idx] = v;
                else                 Vh[idx] = f2bf(v);
            }
        }
    }
}

// ---------------------------------------------------------------------------
// Kernel 2: l2norm (+scale for Q) + RoPE; fp32 in, bf16 out. 1 wave/row.
// ---------------------------------------------------------------------------
__global__ __launch_bounds__(256) void normrope_kernel(
    const float* __restrict__ Qf, const float* __restrict__ Kf,
    unsigned short* __restrict__ Qh, unsigned short* __restrict__ Kh,
    const float* __restrict__ freqs, const float* __restrict__ sml)
{
    int row  = blockIdx.x * 4 + (threadIdx.x >> 6);
    int lane = threadIdx.x & 63;
    const int NROWS = PB * PH * PL;
    bool isQ = row < NROWS;
    int r = isQ ? row : row - NROWS;
    int h = (r >> 10) & (PH - 1);
    int l = r & (PL - 1);

    float v = (isQ ? Qf : Kf)[(size_t)r * PD + lane];
    float ss = v * v;
#pragma unroll
    for (int off = 32; off >= 1; off >>= 1) ss += __shfl_xor(ss, off);
    float scale = 1.0f / fmaxf(sqrtf(ss), 1e-12f);
    if (isQ) scale *= __expf(fminf(sml[h], MAX_SCALE_MUL));
    v *= scale;

    float partner = __shfl_xor(v, 1);
    int i = lane >> 1;
    float c = freqs[(l * 32 + i) * 2 + 0];
    float s = freqs[(l * 32 + i) * 2 + 1];
    float outv = (lane & 1) ? fmaf(partner, s, v * c)
                            : fmaf(v, c, -partner * s);
    (isQ ? Qh : Kh)[(size_t)r * PD + lane] = f2bf(outv);
}

// ---------------------------------------------------------------------------
// Kernel 3: transpose V (B,H,L,D) -> Vt (B,H,D,L), bf16.
// ---------------------------------------------------------------------------
__global__ __launch_bounds__(256) void transpose_v_kernel(
    const unsigned short* __restrict__ Vh, unsigned short* __restrict__ Vt)
{
    int bh = blockIdx.x >> 4;
    int l0 = (blockIdx.x & 15) * 64;
    int tid = threadIdx.x;
#pragma unroll
    for (int s = 0; s < 2; s++) {
        int slot = s * 256 + tid;
        int d  = slot & 63;
        int lb = l0 + (slot >> 6) * 8;
        unsigned o[4];
#pragma unroll
        for (int i = 0; i < 4; i++) {
            unsigned short a0 = Vh[((size_t)bh * PL + lb + 2 * i) * PD + d];
            unsigned short a1 = Vh[((size_t)bh * PL + lb + 2 * i + 1) * PD + d];
            o[i] = (unsigned)a0 | ((unsigned)a1 << 16);
        }
        *(uint4*)&Vt[((size_t)bh * PD + d) * PL + lb] = make_uint4(o[0], o[1], o[2], o[3]);
    }
}

// ---------------------------------------------------------------------------
// Kernel 4: flash attention, S^T/O^T dataflow.
// Block = 64 Q-rows x one (b,h); wave w owns Q-rows w*16..+15.
// S^T = K.Q^T puts q in lane&15, key in quad*4+reg: softmax reduction is
// 15 in-thread ops + 2 shfl; m/l/alpha are per-lane scalars.
// O^T = V^T.P^T; P^T repack via wave-private LDS (4 b64 writes, 2 b128 reads).
// Output written bf16 (B,L,H,D) via LDS-transposed coalesced stores.
// ---------------------------------------------------------------------------
__global__ __launch_bounds__(256) void attn_mfma(
    const unsigned short* __restrict__ Qh, const unsigned short* __restrict__ Kh,
    const unsigned short* __restrict__ Vt, const float* __restrict__ bias,
    unsigned short* __restrict__ O)
{
    __shared__ unsigned short Ks[64 * 64];
    __shared__ unsigned short Vs[64 * 64];
    __shared__ unsigned int   Ps[4][16 * 36];   // per-wave P^T pairs, stride 36

    const int tid  = threadIdx.x;
    const int wave = tid >> 6, lane = tid & 63;
    const int quad = lane >> 4, rr = lane & 15;
    const int bh = blockIdx.y, q0 = blockIdx.x * 64;
    const int b = bh >> 4, h = bh & 15;

    // staging geometry: wave stages rows [wave*16, wave*16+16), 2 instrs each
    const int sr = wave * 16 + (lane >> 3);
    const int sc = lane & 7;
    const int sg = sc ^ (sr & 7);               // swizzled global chunk
    const int swz8 = rr & 7;

    // Q B-fragments direct from global: B[n=q=rr][k=d=quad*8+j]
    const size_t qrow = (size_t)bh * PL + q0 + wave * 16 + rr;
    const s16x8 qB0 = *(const s16x8*)(Qh + qrow * PD + quad * 8);
    const s16x8 qB1 = *(const s16x8*)(Qh + qrow * PD + 32 + quad * 8);

    f32x4 accO[4];
#pragma unroll
    for (int jd = 0; jd < 4; jd++) accO[jd] = (f32x4){0.f, 0.f, 0.f, 0.f};
    float m_i = -3.0e38f, l_i = 0.f;

    const int qglob = q0 + wave * 16 + rr;      // this lane's q row

    for (int kb = 0; kb < 16; kb++) {
        // stage K rows (key x d) and V^T rows (d x key)
        gl2lds16(Kh + ((size_t)bh * PL + kb * 64 + sr) * PD + sg * 8, &Ks[(wave * 16) * 64]);
        gl2lds16(Kh + ((size_t)bh * PL + kb * 64 + sr + 8) * PD + sg * 8, &Ks[(wave * 16 + 8) * 64]);
        gl2lds16(Vt + ((size_t)bh * PD + sr) * PL + kb * 64 + sg * 8, &Vs[(wave * 16) * 64]);
        gl2lds16(Vt + ((size_t)bh * PD + sr + 8) * PL + kb * 64 + sg * 8, &Vs[(wave * 16 + 8) * 64]);
        __syncthreads();

        // S^T subtiles: sub s covers keys s*16+quad*4+reg for this lane's q=rr
        f32x4 sc4[4];
#pragma unroll
        for (int s = 0; s < 4; s++) {
            s16x8 kA0 = *(const s16x8*)&Ks[(s * 16 + rr) * 64 + ((0 + quad) ^ swz8) * 8];
            s16x8 kA1 = *(const s16x8*)&Ks[(s * 16 + rr) * 64 + ((4 + quad) ^ swz8) * 8];
            f32x4 z = (f32x4){0.f, 0.f, 0.f, 0.f};
            z = MFMA16(kA0, qB0, z);
            z = MFMA16(kA1, qB1, z);
            sc4[s] = z;
        }
        // + attn_bias (float4 per sub: keys s*16+quad*4 .. +3)
#pragma unroll
        for (int s = 0; s < 4; s++) {
            float4 bv = *(const float4*)(bias + (size_t)qglob * PL + kb * 64 + s * 16 + quad * 4);
            sc4[s][0] += bv.x; sc4[s][1] += bv.y;
            sc4[s][2] += bv.z; sc4[s][3] += bv.w;
        }

        // online softmax: in-thread over 16 vals, then 2 shfl across quads
        float mt = -3.0e38f;
#pragma unroll
        for (int s = 0; s < 4; s++)
            mt = fmaxf(mt, fmaxf(fmaxf(sc4[s][0], sc4[s][1]), fmaxf(sc4[s][2], sc4[s][3])));
        mt = fmaxf(mt, __shfl_xor(mt, 16));
        mt = fmaxf(mt, __shfl_xor(mt, 32));

        float mn = fmaxf(m_i, mt);
        float al = __expf(m_i - mn);
        m_i = mn;
        float rs = 0.f;
#pragma unroll
        for (int s = 0; s < 4; s++) {
#pragma unroll
            for (int r = 0; r < 4; r++) {
                float p = __expf(sc4[s][r] - mn);
                sc4[s][r] = p;
                rs += p;
            }
        }
        rs += __shfl_xor(rs, 16);
        rs += __shfl_xor(rs, 32);
        l_i = l_i * al + rs;
#pragma unroll
        for (int jd = 0; jd < 4; jd++)
#pragma unroll
            for (int r = 0; r < 4; r++) accO[jd][r] *= al;

        // P^T repack: pair (reg0,reg1)->kp s*8+quad*2, (reg2,reg3)->kp+1
#pragma unroll
        for (int s = 0; s < 4; s++) {
            unsigned p01 = (unsigned)f2bf(sc4[s][0]) | ((unsigned)f2bf(sc4[s][1]) << 16);
            unsigned p23 = (unsigned)f2bf(sc4[s][2]) | ((unsigned)f2bf(sc4[s][3]) << 16);
            *(uint2*)&Ps[wave][rr * 36 + s * 8 + quad * 2] = make_uint2(p01, p23);
        }
        // wave-private read-back as B-frags: kp = quad*4+t (+16 for keys 32..63)
        s16x8 pB0 = *(const s16x8*)&Ps[wave][rr * 36 + quad * 4];
        s16x8 pB1 = *(const s16x8*)&Ps[wave][rr * 36 + 16 + quad * 4];

        // O^T += V^T . P^T
#pragma unroll
        for (int jd = 0; jd < 4; jd++) {
            s16x8 vA0 = *(const s16x8*)&Vs[(jd * 16 + rr) * 64 + ((0 + quad) ^ swz8) * 8];
            s16x8 vA1 = *(const s16x8*)&Vs[(jd * 16 + rr) * 64 + ((4 + quad) ^ swz8) * 8];
            accO[jd] = MFMA16(vA0, pB0, accO[jd]);
            accO[jd] = MFMA16(vA1, pB1, accO[jd]);
        }
        __syncthreads();
    }

    // epilogue: O^T -> LDS (wave-private) -> coalesced (B,L,H,D) stores
    float inv = 1.0f / l_i;
#pragma unroll
    for (int jd = 0; jd < 4; jd++) {
        unsigned o01 = (unsigned)f2bf(accO[jd][0] * inv) | ((unsigned)f2bf(accO[jd][1] * inv) << 16);
        unsigned o23 = (unsigned)f2bf(accO[jd][2] * inv) | ((unsigned)f2bf(accO[jd][3] * inv) << 16);
        *(uint2*)&Ps[wave][rr * 36 + jd * 8 + quad * 2] = make_uint2(o01, o23);
    }
    const int lr = lane >> 2, cch = lane & 3;
    uint4 w0 = *(const uint4*)&Ps[wave][lr * 36 + cch * 8];
    uint4 w1 = *(const uint4*)&Ps[wave][lr * 36 + cch * 8 + 4];
    size_t ob = ((size_t)(b * PL + q0 + wave * 16 + lr) * PC + h * PD);
    *(uint4*)(O + ob + cch * 16)     = w0;
    *(uint4*)(O + ob + cch * 16 + 8) = w1;
}

// ---------------------------------------------------------------------------
// Kernel 5: out-proj GEMM (bf16 MFMA). Out = Oh(8192x1024).Wph(1024x1024)^T + bp
// ---------------------------------------------------------------------------
__global__ __launch_bounds__(256) void gemm_proj_mfma(
    const unsigned short* __restrict__ Ah,
    const unsigned short* __restrict__ Wh,
    const float* __restrict__ bp, float* __restrict__ Out)
{
    __shared__ unsigned short As[128 * 32];
    __shared__ unsigned short Bs[128 * 32];
    const int tid  = threadIdx.x;
    const int wave = tid >> 6, lane = tid & 63;
    const int wm = wave & 1, wn = wave >> 1;
    const int quad = lane >> 4, rr = lane & 15;
    const int m0 = blockIdx.x * 128, n0 = blockIdx.y * 128;

    f32x4 acc[4][4];
#pragma unroll
    for (int i = 0; i < 4; i++)
#pragma unroll
        for (int j = 0; j < 4; j++) acc[i][j] = (f32x4){0.f, 0.f, 0.f, 0.f};

    const int rw = lane >> 2;
    const int cc = lane & 3;
    const int g  = cc ^ ((rw >> 1) & 3);
    const int srow = wave * 32 + rw;
    const unsigned short* gA0 = Ah + (size_t)(m0 + srow) * 1024 + g * 8;
    const unsigned short* gA1 = gA0 + (size_t)16 * 1024;
    const unsigned short* gB0 = Wh + (size_t)(n0 + srow) * 1024 + g * 8;
    const unsigned short* gB1 = gB0 + (size_t)16 * 1024;
    unsigned short* lA0 = &As[(wave * 32) * 32];
    unsigned short* lA1 = &As[(wave * 32 + 16) * 32];
    unsigned short* lB0 = &Bs[(wave * 32) * 32];
    unsigned short* lB1 = &Bs[(wave * 32 + 16) * 32];

    const int swz = (rr >> 1) & 3;
    const int coff = ((quad ^ swz) * 8);

    for (int k0 = 0; k0 < 1024; k0 += 32) {
        gl2lds16(gA0, lA0); gl2lds16(gA1, lA1);
        gl2lds16(gB0, lB0); gl2lds16(gB1, lB1);
        gA0 += 32; gA1 += 32; gB0 += 32; gB1 += 32;
        __syncthreads();

        s16x8 af[4], bf[4];
#pragma unroll
        for (int i = 0; i < 4; i++)
            af[i] = *(const s16x8*)&As[(wm * 64 + i * 16 + rr) * 32 + coff];
#pragma unroll
        for (int j = 0; j < 4; j++)
            bf[j] = *(const s16x8*)&Bs[(wn * 64 + j * 16 + rr) * 32 + coff];
#pragma unroll
        for (int i = 0; i < 4; i++)
#pragma unroll
            for (int j = 0; j < 4; j++)
                acc[i][j] = MFMA16(af[i], bf[j], acc[i][j]);
        __syncthreads();
    }

#pragma unroll
    for (int i = 0; i < 4; i++) {
        const int mb = m0 + wm * 64 + i * 16 + quad * 4;
#pragma unroll
        for (int j = 0; j < 4; j++) {
            const int n = n0 + wn * 64 + j * 16 + rr;
            const float bb = bp[n];
#pragma unroll
            for (int reg = 0; reg < 4; reg++)
                Out[(size_t)(mb + reg) * 1024 + n] = acc[i][j][reg] + bb;
        }
    }
}

// ---------------------------------------------------------------------------
extern "C" void kernel_launch(void* const* d_in, const int* in_sizes, int n_in,
                              void* d_out, int out_size, void* d_ws, size_t ws_size,
                              hipStream_t stream)
{
    const float* x         = (const float*)d_in[0];
    const float* freqs     = (const float*)d_in[1];
    const float* attn_bias = (const float*)d_in[2];
    const float* W_qkv     = (const float*)d_in[3];
    const float* q_bias    = (const float*)d_in[4];
    const float* v_bias    = (const float*)d_in[5];
    const float* sml       = (const float*)d_in[6];
    const float* W_proj    = (const float*)d_in[7];
    const float* b_proj    = (const float*)d_in[8];
    float* out = (float*)d_out;

    unsigned char* w = (unsigned char*)d_ws;
    const size_t MB = 1ull << 20;
    unsigned short* xh  = (unsigned short*)(w + 0);        // 16 MiB, dead after qkv
    unsigned short* wqh = (unsigned short*)(w + 16 * MB);  //  6 MiB, dead after qkv
    unsigned short* wph = (unsigned short*)(w + 22 * MB);  //  2 MiB, live till proj
    float*          Qf  = (float*)(w + 24 * MB);           // 32 MiB, dead after normrope
    float*          Kf  = (float*)(w + 56 * MB);           // 32 MiB, dead after normrope
    unsigned short* Vh  = (unsigned short*)(w + 88 * MB);  // 16 MiB, dead after transpose
    unsigned short* Qh  = (unsigned short*)(w + 0);        // overlays xh
    unsigned short* Kh  = (unsigned short*)(w + 104 * MB); // 16 MiB
    unsigned short* Vt  = (unsigned short*)(w + 24 * MB);  // overlays Qf[0:16M]
    unsigned short* Oh  = (unsigned short*)(w + 40 * MB);  // overlays Qf[16M:32M]

    cast_bf16_kernel<<<8192, 256, 0, stream>>>(x, xh);
    cast_bf16_kernel<<<3072, 256, 0, stream>>>(W_qkv, wqh);
    cast_bf16_kernel<<<1024, 256, 0, stream>>>(W_proj, wph);
    gemm_qkv_mfma<<<dim3(64, 24), 256, 0, stream>>>(xh, wqh, q_bias, v_bias, Qf, Kf, Vh);
    normrope_kernel<<<65536, 256, 0, stream>>>(Qf, Kf, Qh, Kh, freqs, sml);
    transpose_v_kernel<<<2048, 256, 0, stream>>>(Vh, Vt);
    attn_mfma<<<dim3(16, 128), 256, 0, stream>>>(Qh, Kh, Vt, attn_bias, Oh);
    gemm_proj_mfma<<<dim3(64, 8), 256, 0, stream>>>(Oh, wph, b_proj, out);
}

// Round 4
// 349.327 us; speedup vs baseline: 4.3305x; 1.0014x over previous
//
#include <hip/hip_runtime.h>
#include <math.h>

#define PB 8
#define PL 1024
#define PC 1024
#define PH 16
#define PD 64
#define MAX_SCALE_MUL 4.605170185988092f  // log(100)
#define LOG2E 1.4426950408889634f

typedef __attribute__((ext_vector_type(8))) short s16x8;
typedef __attribute__((ext_vector_type(4))) float f32x4;

#define MFMA16(a, b, c) __builtin_amdgcn_mfma_f32_16x16x32_bf16(a, b, c, 0, 0, 0)

#if __has_builtin(__builtin_amdgcn_exp2f)
#define EXP2(x) __builtin_amdgcn_exp2f(x)
#else
#define EXP2(x) exp2f(x)
#endif

// fp32 -> bf16 round-to-nearest-even
__device__ __forceinline__ unsigned short f2bf(float f) {
    unsigned u = __float_as_uint(f);
    unsigned r = (u + 0x7fffu + ((u >> 16) & 1u)) >> 16;
    return (unsigned short)r;
}

// async global->LDS, 16 bytes per lane; lptr must be wave-uniform
__device__ __forceinline__ void gl2lds16(const void* g, void* l) {
    __builtin_amdgcn_global_load_lds(
        (const __attribute__((address_space(1))) unsigned int*)g,
        (__attribute__((address_space(3))) unsigned int*)l, 16, 0, 0);
}

// ---------------------------------------------------------------------------
// cast fp32 -> bf16 for x, W_qkv, W_proj in one launch.
// blocks [0,8192) -> x, [8192,11264) -> W_qkv, [11264,12288) -> W_proj
// ---------------------------------------------------------------------------
__global__ __launch_bounds__(256) void cast3_kernel(
    const float* __restrict__ a, const float* __restrict__ b,
    const float* __restrict__ c,
    unsigned short* __restrict__ oa, unsigned short* __restrict__ ob,
    unsigned short* __restrict__ oc)
{
    int blk = blockIdx.x;
    const float* src; unsigned short* dst; int base;
    if (blk < 8192)       { src = a; dst = oa; base = blk; }
    else if (blk < 11264) { src = b; dst = ob; base = blk - 8192; }
    else                  { src = c; dst = oc; base = blk - 11264; }
    int i = base * 256 + threadIdx.x;
    float4 v = ((const float4*)src)[i];
    unsigned p0 = (unsigned)f2bf(v.x) | ((unsigned)f2bf(v.y) << 16);
    unsigned p1 = (unsigned)f2bf(v.z) | ((unsigned)f2bf(v.w) << 16);
    ((uint2*)dst)[i] = make_uint2(p0, p1);
}

// ---------------------------------------------------------------------------
// Kernel 1: QKV GEMM (bf16 MFMA) with FUSED epilogue:
//   Q: +q_bias, l2norm, *exp(min(sml,MAX))*log2e, RoPE -> bf16 (B,H,L,D)
//   K: l2norm, RoPE -> bf16 (B,H,L,D)
//   V: +v_bias -> bf16 DIRECTLY TRANSPOSED to (B,H,D,L)
// A wave's 64 columns = exactly one head, so norm reduces across the 16
// rr-lanes (shfl_xor 1/2/4/8) after 4 in-thread squares.
// ---------------------------------------------------------------------------
__global__ __launch_bounds__(256) void gemm_qkv_fused(
    const unsigned short* __restrict__ Xh,
    const unsigned short* __restrict__ Wh,
    const float* __restrict__ qb, const float* __restrict__ vb,
    const float* __restrict__ freqs,   // (1024,32,2) fp32
    const float* __restrict__ sml,     // (16)
    unsigned short* __restrict__ Qh, unsigned short* __restrict__ Kh,
    unsigned short* __restrict__ Vt)
{
    __shared__ unsigned short As[128 * 32];
    __shared__ unsigned short Bs[128 * 32];
    const int tid  = threadIdx.x;
    const int wave = tid >> 6, lane = tid & 63;
    const int wm = wave & 1, wn = wave >> 1;
    const int quad = lane >> 4, rr = lane & 15;
    const int m0 = blockIdx.x * 128, n0 = blockIdx.y * 128;

    f32x4 acc[4][4];
#pragma unroll
    for (int i = 0; i < 4; i++)
#pragma unroll
        for (int j = 0; j < 4; j++) acc[i][j] = (f32x4){0.f, 0.f, 0.f, 0.f};

    const int rw = lane >> 2;
    const int cc = lane & 3;
    const int g  = cc ^ ((rw >> 1) & 3);
    const int srow = wave * 32 + rw;
    const unsigned short* gA0 = Xh + (size_t)(m0 + srow) * 1024 + g * 8;
    const unsigned short* gA1 = gA0 + (size_t)16 * 1024;
    const unsigned short* gB0 = Wh + (size_t)(n0 + srow) * 1024 + g * 8;
    const unsigned short* gB1 = gB0 + (size_t)16 * 1024;
    unsigned short* lA0 = &As[(wave * 32) * 32];
    unsigned short* lA1 = &As[(wave * 32 + 16) * 32];
    unsigned short* lB0 = &Bs[(wave * 32) * 32];
    unsigned short* lB1 = &Bs[(wave * 32 + 16) * 32];

    const int swz = (rr >> 1) & 3;
    const int coff = ((quad ^ swz) * 8);

    for (int k0 = 0; k0 < 1024; k0 += 32) {
        gl2lds16(gA0, lA0); gl2lds16(gA1, lA1);
        gl2lds16(gB0, lB0); gl2lds16(gB1, lB1);
        gA0 += 32; gA1 += 32; gB0 += 32; gB1 += 32;
        __syncthreads();

        s16x8 af[4], bf[4];
#pragma unroll
        for (int i = 0; i < 4; i++)
            af[i] = *(const s16x8*)&As[(wm * 64 + i * 16 + rr) * 32 + coff];
#pragma unroll
        for (int j = 0; j < 4; j++)
            bf[j] = *(const s16x8*)&Bs[(wn * 64 + j * 16 + rr) * 32 + coff];
#pragma unroll
        for (int i = 0; i < 4; i++)
#pragma unroll
            for (int j = 0; j < 4; j++)
                acc[i][j] = MFMA16(af[i], bf[j], acc[i][j]);
        __syncthreads();
    }

    // ---- fused epilogue ----
    const int b     = m0 >> 10;
    const int which = n0 >> 10;                       // uniform: 0=Q 1=K 2=V
    const int h     = ((n0 & 1023) + wn * 64) >> 6;   // head (uniform per wave)
    const int lb0   = (m0 & 1023) + wm * 64;          // base l for this wave

    if (which == 2) {
        // V: +bias, bf16, direct transposed store (B,H,D,L)
#pragma unroll
        for (int j = 0; j < 4; j++) {
            const int d = j * 16 + rr;
            const float bias = vb[h * 64 + d];
            unsigned short* vrow = Vt + ((size_t)(b * PH + h) * PD + d) * PL;
#pragma unroll
            for (int i = 0; i < 4; i++) {
                const int l = lb0 + i * 16 + quad * 4;
#pragma unroll
                for (int reg = 0; reg < 4; reg++)
                    vrow[l + reg] = f2bf(acc[i][j][reg] + bias);
            }
        }
        return;
    }

    // Q/K path
    float smul = 1.0f;
    if (which == 0) {
        smul = __expf(fminf(sml[h], MAX_SCALE_MUL)) * LOG2E;
        // q_bias add
#pragma unroll
        for (int j = 0; j < 4; j++) {
            const float qbv = qb[h * 64 + j * 16 + rr];
#pragma unroll
            for (int i = 0; i < 4; i++)
#pragma unroll
                for (int reg = 0; reg < 4; reg++) acc[i][j][reg] += qbv;
        }
    }
    unsigned short* dst = (which == 0) ? Qh : Kh;
    const float2* fr2 = (const float2*)freqs;

#pragma unroll
    for (int i = 0; i < 4; i++) {
        // per-row sum of squares: in-thread over j, then across rr lanes
        float ss[4];
#pragma unroll
        for (int reg = 0; reg < 4; reg++) {
            float t = 0.f;
#pragma unroll
            for (int j = 0; j < 4; j++) t = fmaf(acc[i][j][reg], acc[i][j][reg], t);
            ss[reg] = t;
        }
#pragma unroll
        for (int off = 1; off < 16; off <<= 1)
#pragma unroll
            for (int reg = 0; reg < 4; reg++) ss[reg] += __shfl_xor(ss[reg], off);

        float scl[4];
#pragma unroll
        for (int reg = 0; reg < 4; reg++)
            scl[reg] = smul / fmaxf(sqrtf(ss[reg]), 1e-12f);

        const int lq = lb0 + i * 16 + quad * 4;       // + reg
#pragma unroll
        for (int j = 0; j < 4; j++) {
            const int d = j * 16 + rr;
            const int fi = j * 8 + (rr >> 1);
#pragma unroll
            for (int reg = 0; reg < 4; reg++) {
                float v = acc[i][j][reg] * scl[reg];
                float p = __shfl_xor(v, 1);
                float2 cs = fr2[(size_t)(lq + reg) * 32 + fi];
                float outv = fmaf(p, (rr & 1) ? cs.y : -cs.y, v * cs.x);
                dst[((size_t)(b * PH + h) * PL + lq + reg) * PD + d] = f2bf(outv);
            }
        }
    }
}

// ---------------------------------------------------------------------------
// Kernel 2: flash attention, S^T/O^T dataflow, exp2 domain.
// Q is pre-scaled by log2e; bias folded via fma(bias, LOG2E, s).
// ---------------------------------------------------------------------------
__global__ __launch_bounds__(256) void attn_mfma(
    const unsigned short* __restrict__ Qh, const unsigned short* __restrict__ Kh,
    const unsigned short* __restrict__ Vt, const float* __restrict__ bias,
    unsigned short* __restrict__ O)
{
    __shared__ unsigned short Ks[64 * 64];
    __shared__ unsigned short Vs[64 * 64];
    __shared__ unsigned int   Ps[4][16 * 36];   // per-wave P^T pairs, stride 36

    const int tid  = threadIdx.x;
    const int wave = tid >> 6, lane = tid & 63;
    const int quad = lane >> 4, rr = lane & 15;
    const int bh = blockIdx.y, q0 = blockIdx.x * 64;
    const int b = bh >> 4, h = bh & 15;

    const int sr = wave * 16 + (lane >> 3);
    const int sc = lane & 7;
    const int sg = sc ^ (sr & 7);               // swizzled global chunk
    const int swz8 = rr & 7;

    // Q B-fragments direct from global: B[n=q=rr][k=d=quad*8+j]
    const size_t qrow = (size_t)bh * PL + q0 + wave * 16 + rr;
    const s16x8 qB0 = *(const s16x8*)(Qh + qrow * PD + quad * 8);
    const s16x8 qB1 = *(const s16x8*)(Qh + qrow * PD + 32 + quad * 8);

    f32x4 accO[4];
#pragma unroll
    for (int jd = 0; jd < 4; jd++) accO[jd] = (f32x4){0.f, 0.f, 0.f, 0.f};
    float m_i = -3.0e38f, l_i = 0.f;

    const int qglob = q0 + wave * 16 + rr;

    for (int kb = 0; kb < 16; kb++) {
        gl2lds16(Kh + ((size_t)bh * PL + kb * 64 + sr) * PD + sg * 8, &Ks[(wave * 16) * 64]);
        gl2lds16(Kh + ((size_t)bh * PL + kb * 64 + sr + 8) * PD + sg * 8, &Ks[(wave * 16 + 8) * 64]);
        gl2lds16(Vt + ((size_t)bh * PD + sr) * PL + kb * 64 + sg * 8, &Vs[(wave * 16) * 64]);
        gl2lds16(Vt + ((size_t)bh * PD + sr + 8) * PL + kb * 64 + sg * 8, &Vs[(wave * 16 + 8) * 64]);
        __syncthreads();

        // S^T subtiles (already in log2 domain via Q scaling)
        f32x4 sc4[4];
#pragma unroll
        for (int s = 0; s < 4; s++) {
            s16x8 kA0 = *(const s16x8*)&Ks[(s * 16 + rr) * 64 + ((0 + quad) ^ swz8) * 8];
            s16x8 kA1 = *(const s16x8*)&Ks[(s * 16 + rr) * 64 + ((4 + quad) ^ swz8) * 8];
            f32x4 z = (f32x4){0.f, 0.f, 0.f, 0.f};
            z = MFMA16(kA0, qB0, z);
            z = MFMA16(kA1, qB1, z);
            sc4[s] = z;
        }
#pragma unroll
        for (int s = 0; s < 4; s++) {
            float4 bv = *(const float4*)(bias + (size_t)qglob * PL + kb * 64 + s * 16 + quad * 4);
            sc4[s][0] = fmaf(bv.x, LOG2E, sc4[s][0]);
            sc4[s][1] = fmaf(bv.y, LOG2E, sc4[s][1]);
            sc4[s][2] = fmaf(bv.z, LOG2E, sc4[s][2]);
            sc4[s][3] = fmaf(bv.w, LOG2E, sc4[s][3]);
        }

        // online softmax (log2 domain)
        float mt = -3.0e38f;
#pragma unroll
        for (int s = 0; s < 4; s++)
            mt = fmaxf(mt, fmaxf(fmaxf(sc4[s][0], sc4[s][1]), fmaxf(sc4[s][2], sc4[s][3])));
        mt = fmaxf(mt, __shfl_xor(mt, 16));
        mt = fmaxf(mt, __shfl_xor(mt, 32));

        float mn = fmaxf(m_i, mt);
        float al = EXP2(m_i - mn);
        m_i = mn;
        float rs = 0.f;
#pragma unroll
        for (int s = 0; s < 4; s++) {
#pragma unroll
            for (int r = 0; r < 4; r++) {
                float p = EXP2(sc4[s][r] - mn);
                sc4[s][r] = p;
                rs += p;
            }
        }
        rs += __shfl_xor(rs, 16);
        rs += __shfl_xor(rs, 32);
        l_i = l_i * al + rs;
#pragma unroll
        for (int jd = 0; jd < 4; jd++)
#pragma unroll
            for (int r = 0; r < 4; r++) accO[jd][r] *= al;

        // P^T repack via wave-private LDS
#pragma unroll
        for (int s = 0; s < 4; s++) {
            unsigned p01 = (unsigned)f2bf(sc4[s][0]) | ((unsigned)f2bf(sc4[s][1]) << 16);
            unsigned p23 = (unsigned)f2bf(sc4[s][2]) | ((unsigned)f2bf(sc4[s][3]) << 16);
            *(uint2*)&Ps[wave][rr * 36 + s * 8 + quad * 2] = make_uint2(p01, p23);
        }
        s16x8 pB0 = *(const s16x8*)&Ps[wave][rr * 36 + quad * 4];
        s16x8 pB1 = *(const s16x8*)&Ps[wave][rr * 36 + 16 + quad * 4];

        // O^T += V^T . P^T
#pragma unroll
        for (int jd = 0; jd < 4; jd++) {
            s16x8 vA0 = *(const s16x8*)&Vs[(jd * 16 + rr) * 64 + ((0 + quad) ^ swz8) * 8];
            s16x8 vA1 = *(const s16x8*)&Vs[(jd * 16 + rr) * 64 + ((4 + quad) ^ swz8) * 8];
            accO[jd] = MFMA16(vA0, pB0, accO[jd]);
            accO[jd] = MFMA16(vA1, pB1, accO[jd]);
        }
        __syncthreads();
    }

    // epilogue: O^T -> LDS -> coalesced (B,L,H,D) stores
    float inv = 1.0f / l_i;
#pragma unroll
    for (int jd = 0; jd < 4; jd++) {
        unsigned o01 = (unsigned)f2bf(accO[jd][0] * inv) | ((unsigned)f2bf(accO[jd][1] * inv) << 16);
        unsigned o23 = (unsigned)f2bf(accO[jd][2] * inv) | ((unsigned)f2bf(accO[jd][3] * inv) << 16);
        *(uint2*)&Ps[wave][rr * 36 + jd * 8 + quad * 2] = make_uint2(o01, o23);
    }
    const int lr = lane >> 2, cch = lane & 3;
    uint4 w0 = *(const uint4*)&Ps[wave][lr * 36 + cch * 8];
    uint4 w1 = *(const uint4*)&Ps[wave][lr * 36 + cch * 8 + 4];
    size_t ob = ((size_t)(b * PL + q0 + wave * 16 + lr) * PC + h * PD);
    *(uint4*)(O + ob + cch * 16)     = w0;
    *(uint4*)(O + ob + cch * 16 + 8) = w1;
}

// ---------------------------------------------------------------------------
// Kernel 3: out-proj GEMM (bf16 MFMA). Out = Oh(8192x1024).Wph(1024x1024)^T + bp
// ---------------------------------------------------------------------------
__global__ __launch_bounds__(256) void gemm_proj_mfma(
    const unsigned short* __restrict__ Ah,
    const unsigned short* __restrict__ Wh,
    const float* __restrict__ bp, float* __restrict__ Out)
{
    __shared__ unsigned short As[128 * 32];
    __shared__ unsigned short Bs[128 * 32];
    const int tid  = threadIdx.x;
    const int wave = tid >> 6, lane = tid & 63;
    const int wm = wave & 1, wn = wave >> 1;
    const int quad = lane >> 4, rr = lane & 15;
    const int m0 = blockIdx.x * 128, n0 = blockIdx.y * 128;

    f32x4 acc[4][4];
#pragma unroll
    for (int i = 0; i < 4; i++)
#pragma unroll
        for (int j = 0; j < 4; j++) acc[i][j] = (f32x4){0.f, 0.f, 0.f, 0.f};

    const int rw = lane >> 2;
    const int cc = lane & 3;
    const int g  = cc ^ ((rw >> 1) & 3);
    const int srow = wave * 32 + rw;
    const unsigned short* gA0 = Ah + (size_t)(m0 + srow) * 1024 + g * 8;
    const unsigned short* gA1 = gA0 + (size_t)16 * 1024;
    const unsigned short* gB0 = Wh + (size_t)(n0 + srow) * 1024 + g * 8;
    const unsigned short* gB1 = gB0 + (size_t)16 * 1024;
    unsigned short* lA0 = &As[(wave * 32) * 32];
    unsigned short* lA1 = &As[(wave * 32 + 16) * 32];
    unsigned short* lB0 = &Bs[(wave * 32) * 32];
    unsigned short* lB1 = &Bs[(wave * 32 + 16) * 32];

    const int swz = (rr >> 1) & 3;
    const int coff = ((quad ^ swz) * 8);

    for (int k0 = 0; k0 < 1024; k0 += 32) {
        gl2lds16(gA0, lA0); gl2lds16(gA1, lA1);
        gl2lds16(gB0, lB0); gl2lds16(gB1, lB1);
        gA0 += 32; gA1 += 32; gB0 += 32; gB1 += 32;
        __syncthreads();

        s16x8 af[4], bf[4];
#pragma unroll
        for (int i = 0; i < 4; i++)
            af[i] = *(const s16x8*)&As[(wm * 64 + i * 16 + rr) * 32 + coff];
#pragma unroll
        for (int j = 0; j < 4; j++)
            bf[j] = *(const s16x8*)&Bs[(wn * 64 + j * 16 + rr) * 32 + coff];
#pragma unroll
        for (int i = 0; i < 4; i++)
#pragma unroll
            for (int j = 0; j < 4; j++)
                acc[i][j] = MFMA16(af[i], bf[j], acc[i][j]);
        __syncthreads();
    }

#pragma unroll
    for (int i = 0; i < 4; i++) {
        const int mb = m0 + wm * 64 + i * 16 + quad * 4;
#pragma unroll
        for (int j = 0; j < 4; j++) {
            const int n = n0 + wn * 64 + j * 16 + rr;
            const float bb = bp[n];
#pragma unroll
            for (int reg = 0; reg < 4; reg++)
                Out[(size_t)(mb + reg) * 1024 + n] = acc[i][j][reg] + bb;
        }
    }
}

// ---------------------------------------------------------------------------
extern "C" void kernel_launch(void* const* d_in, const int* in_sizes, int n_in,
                              void* d_out, int out_size, void* d_ws, size_t ws_size,
                              hipStream_t stream)
{
    const float* x         = (const float*)d_in[0];
    const float* freqs     = (const float*)d_in[1];
    const float* attn_bias = (const float*)d_in[2];
    const float* W_qkv     = (const float*)d_in[3];
    const float* q_bias    = (const float*)d_in[4];
    const float* v_bias    = (const float*)d_in[5];
    const float* sml       = (const float*)d_in[6];
    const float* W_proj    = (const float*)d_in[7];
    const float* b_proj    = (const float*)d_in[8];
    float* out = (float*)d_out;

    unsigned char* w = (unsigned char*)d_ws;
    const size_t MB = 1ull << 20;
    unsigned short* xh  = (unsigned short*)(w + 0);        // 16 MiB
    unsigned short* wqh = (unsigned short*)(w + 16 * MB);  //  6 MiB
    unsigned short* wph = (unsigned short*)(w + 22 * MB);  //  2 MiB
    unsigned short* Qh  = (unsigned short*)(w + 24 * MB);  // 16 MiB
    unsigned short* Kh  = (unsigned short*)(w + 40 * MB);  // 16 MiB
    unsigned short* Vt  = (unsigned short*)(w + 56 * MB);  // 16 MiB (B,H,D,L)
    unsigned short* Oh  = (unsigned short*)(w + 72 * MB);  // 16 MiB (B,L,H,D)

    // 1. fused casts
    cast3_kernel<<<12288, 256, 0, stream>>>(x, W_qkv, W_proj, xh, wqh, wph);
    // 2. QKV projection + norm + RoPE + V-transpose (fused)
    gemm_qkv_fused<<<dim3(64, 24), 256, 0, stream>>>(xh, wqh, q_bias, v_bias,
                                                     freqs, sml, Qh, Kh, Vt);
    // 3. flash attention (exp2 domain)
    attn_mfma<<<dim3(16, 128), 256, 0, stream>>>(Qh, Kh, Vt, attn_bias, Oh);
    // 4. output projection
    gemm_proj_mfma<<<dim3(64, 8), 256, 0, stream>>>(Oh, wph, b_proj, out);
}

// Round 5
// 318.546 us; speedup vs baseline: 4.7490x; 1.0966x over previous
//
#include <hip/hip_runtime.h>
#include <math.h>

#define PB 8
#define PL 1024
#define PC 1024
#define PH 16
#define PD 64
#define MAX_SCALE_MUL 4.605170185988092f  // log(100)
#define LOG2E 1.4426950408889634f

typedef __attribute__((ext_vector_type(8))) short s16x8;
typedef __attribute__((ext_vector_type(4))) float f32x4;

#define MFMA16(a, b, c) __builtin_amdgcn_mfma_f32_16x16x32_bf16(a, b, c, 0, 0, 0)

#if __has_builtin(__builtin_amdgcn_exp2f)
#define EXP2(x) __builtin_amdgcn_exp2f(x)
#else
#define EXP2(x) exp2f(x)
#endif

// fp32 -> bf16 round-to-nearest-even
__device__ __forceinline__ unsigned short f2bf(float f) {
    unsigned u = __float_as_uint(f);
    unsigned r = (u + 0x7fffu + ((u >> 16) & 1u)) >> 16;
    return (unsigned short)r;
}

// async global->LDS, 16 bytes per lane; lptr must be wave-uniform
__device__ __forceinline__ void gl2lds16(const void* g, void* l) {
    __builtin_amdgcn_global_load_lds(
        (const __attribute__((address_space(1))) unsigned int*)g,
        (__attribute__((address_space(3))) unsigned int*)l, 16, 0, 0);
}

// ---------------------------------------------------------------------------
// cast fp32 -> bf16 for x, W_qkv, W_proj in one launch.
// ---------------------------------------------------------------------------
__global__ __launch_bounds__(256) void cast3_kernel(
    const float* __restrict__ a, const float* __restrict__ b,
    const float* __restrict__ c,
    unsigned short* __restrict__ oa, unsigned short* __restrict__ ob,
    unsigned short* __restrict__ oc)
{
    int blk = blockIdx.x;
    const float* src; unsigned short* dst; int base;
    if (blk < 8192)       { src = a; dst = oa; base = blk; }
    else if (blk < 11264) { src = b; dst = ob; base = blk - 8192; }
    else                  { src = c; dst = oc; base = blk - 11264; }
    int i = base * 256 + threadIdx.x;
    float4 v = ((const float4*)src)[i];
    unsigned p0 = (unsigned)f2bf(v.x) | ((unsigned)f2bf(v.y) << 16);
    unsigned p1 = (unsigned)f2bf(v.z) | ((unsigned)f2bf(v.w) << 16);
    ((uint2*)dst)[i] = make_uint2(p0, p1);
}

// ---------------------------------------------------------------------------
// Kernel 1: LEAN QKV GEMM (bf16 MFMA). Writes raw bf16 Q/K/V (+bias) in
// (B,H,L,D). Norm/RoPE/transpose deferred to the memory-bound postproc
// kernel to keep VGPR low and occupancy high (R4 lesson: fat epilogue ->
// 136 VGPR -> 11% occupancy -> latency-bound GEMM).
// ---------------------------------------------------------------------------
__global__ __launch_bounds__(256) void gemm_qkv_lean(
    const unsigned short* __restrict__ Xh,
    const unsigned short* __restrict__ Wh,
    const float* __restrict__ qb, const float* __restrict__ vb,
    unsigned short* __restrict__ Qh, unsigned short* __restrict__ Kh,
    unsigned short* __restrict__ Vh)
{
    __shared__ unsigned short As[128 * 32];
    __shared__ unsigned short Bs[128 * 32];
    const int tid  = threadIdx.x;
    const int wave = tid >> 6, lane = tid & 63;
    const int wm = wave & 1, wn = wave >> 1;
    const int quad = lane >> 4, rr = lane & 15;
    const int m0 = blockIdx.x * 128, n0 = blockIdx.y * 128;

    f32x4 acc[4][4];
#pragma unroll
    for (int i = 0; i < 4; i++)
#pragma unroll
        for (int j = 0; j < 4; j++) acc[i][j] = (f32x4){0.f, 0.f, 0.f, 0.f};

    const int rw = lane >> 2;
    const int cc = lane & 3;
    const int g  = cc ^ ((rw >> 1) & 3);
    const int srow = wave * 32 + rw;
    const unsigned short* gA0 = Xh + (size_t)(m0 + srow) * 1024 + g * 8;
    const unsigned short* gA1 = gA0 + (size_t)16 * 1024;
    const unsigned short* gB0 = Wh + (size_t)(n0 + srow) * 1024 + g * 8;
    const unsigned short* gB1 = gB0 + (size_t)16 * 1024;
    unsigned short* lA0 = &As[(wave * 32) * 32];
    unsigned short* lA1 = &As[(wave * 32 + 16) * 32];
    unsigned short* lB0 = &Bs[(wave * 32) * 32];
    unsigned short* lB1 = &Bs[(wave * 32 + 16) * 32];

    const int swz = (rr >> 1) & 3;
    const int coff = ((quad ^ swz) * 8);

    for (int k0 = 0; k0 < 1024; k0 += 32) {
        gl2lds16(gA0, lA0); gl2lds16(gA1, lA1);
        gl2lds16(gB0, lB0); gl2lds16(gB1, lB1);
        gA0 += 32; gA1 += 32; gB0 += 32; gB1 += 32;
        __syncthreads();

        s16x8 af[4], bf[4];
#pragma unroll
        for (int i = 0; i < 4; i++)
            af[i] = *(const s16x8*)&As[(wm * 64 + i * 16 + rr) * 32 + coff];
#pragma unroll
        for (int j = 0; j < 4; j++)
            bf[j] = *(const s16x8*)&Bs[(wn * 64 + j * 16 + rr) * 32 + coff];
#pragma unroll
        for (int i = 0; i < 4; i++)
#pragma unroll
            for (int j = 0; j < 4; j++)
                acc[i][j] = MFMA16(af[i], bf[j], acc[i][j]);
        __syncthreads();
    }

    // slim epilogue: bias + bf16 store to (B,H,L,D)
    const int b     = m0 >> 10;
    const int which = n0 >> 10;                       // 0=Q 1=K 2=V (uniform)
    const int h     = ((n0 & 1023) + wn * 64) >> 6;   // head (uniform per wave)
    const int lb0   = (m0 & 1023) + wm * 64;
    unsigned short* dst = (which == 0) ? Qh : ((which == 1) ? Kh : Vh);
    unsigned short* base = dst + ((size_t)(b * PH + h) * PL) * PD;

#pragma unroll
    for (int j = 0; j < 4; j++) {
        const int d = j * 16 + rr;
        float bias = 0.f;
        if (which == 0) bias = qb[h * 64 + d];
        if (which == 2) bias = vb[h * 64 + d];
#pragma unroll
        for (int i = 0; i < 4; i++) {
            const int l = lb0 + i * 16 + quad * 4;
#pragma unroll
            for (int reg = 0; reg < 4; reg++)
                base[(size_t)(l + reg) * PD + d] = f2bf(acc[i][j][reg] + bias);
        }
    }
}

// ---------------------------------------------------------------------------
// Kernel 2: fused postprocess (3 roles by block range).
//  [0,16384):      Q norm + *exp(min(sml,MAX))*log2e + RoPE, in place (bf16)
//  [16384,32768):  K norm + RoPE, in place (bf16)
//  [32768,34816):  V transpose (B,H,L,D) -> (B,H,D,L)
// Q/K: wave = 2 rows x 32 lanes; lane's uint load = RoPE pair (d=2i,2i+1),
// so rotation is fully in-thread; norm = 5 shfl_xor within the 32-half.
// ---------------------------------------------------------------------------
__global__ __launch_bounds__(256) void postproc_kernel(
    unsigned short* __restrict__ Qh, unsigned short* __restrict__ Kh,
    const unsigned short* __restrict__ Vh, unsigned short* __restrict__ Vt,
    const float* __restrict__ freqs, const float* __restrict__ sml)
{
    const int blk = blockIdx.x;
    const int tid = threadIdx.x;

    if (blk < 32768) {
        const bool isQ = blk < 16384;
        const int rb = isQ ? blk : blk - 16384;
        const int row = rb * 8 + (tid >> 5);       // 8 rows per block
        const int li  = tid & 31;                  // pair index within row
        const int h = (row >> 10) & (PH - 1);
        const int l = row & (PL - 1);

        unsigned short* buf = isQ ? Qh : Kh;
        unsigned* p = (unsigned*)(buf + (size_t)row * PD) + li;
        unsigned v = *p;
        float v0 = __uint_as_float(v << 16);
        float v1 = __uint_as_float(v & 0xffff0000u);

        float ss = fmaf(v0, v0, v1 * v1);
#pragma unroll
        for (int off = 1; off <= 16; off <<= 1) ss += __shfl_xor(ss, off);

        float smul = isQ ? (__expf(fminf(sml[h], MAX_SCALE_MUL)) * LOG2E) : 1.0f;
        float scale = smul / fmaxf(sqrtf(ss), 1e-12f);
        v0 *= scale; v1 *= scale;

        float2 cs = ((const float2*)freqs)[l * 32 + li];
        float re = v0 * cs.x - v1 * cs.y;
        float im = fmaf(v0, cs.y, v1 * cs.x);
        *p = (unsigned)f2bf(re) | ((unsigned)f2bf(im) << 16);
        return;
    }

    // V transpose
    const int vblk = blk - 32768;
    const int bh = vblk >> 4;
    const int l0 = (vblk & 15) * 64;
#pragma unroll
    for (int s = 0; s < 2; s++) {
        int slot = s * 256 + tid;
        int d  = slot & 63;
        int lb = l0 + (slot >> 6) * 8;
        unsigned o[4];
#pragma unroll
        for (int i = 0; i < 4; i++) {
            unsigned short a0 = Vh[((size_t)bh * PL + lb + 2 * i) * PD + d];
            unsigned short a1 = Vh[((size_t)bh * PL + lb + 2 * i + 1) * PD + d];
            o[i] = (unsigned)a0 | ((unsigned)a1 << 16);
        }
        *(uint4*)&Vt[((size_t)bh * PD + d) * PL + lb] = make_uint4(o[0], o[1], o[2], o[3]);
    }
}

// ---------------------------------------------------------------------------
// Kernel 3: flash attention with STATIC-BOUND softmax (exp2 domain).
// q rows are l2-normalized * smul and pre-scaled by log2e; k rows are unit,
// so score_log2 <= M = smul*log2e (Cauchy-Schwarz). Fixed shift M makes the
// softmax shift-exact (cancels in p/l): no max reduction, no rescaling,
// no m-tracking. l reduced cross-quad once at the end.
// ---------------------------------------------------------------------------
__global__ __launch_bounds__(256) void attn_mfma(
    const unsigned short* __restrict__ Qh, const unsigned short* __restrict__ Kh,
    const unsigned short* __restrict__ Vt, const float* __restrict__ bias,
    const float* __restrict__ sml, unsigned short* __restrict__ O)
{
    __shared__ unsigned short Ks[64 * 64];
    __shared__ unsigned short Vs[64 * 64];
    __shared__ unsigned int   Ps[4][16 * 36];   // per-wave P^T pairs, stride 36

    const int tid  = threadIdx.x;
    const int wave = tid >> 6, lane = tid & 63;
    const int quad = lane >> 4, rr = lane & 15;
    const int bh = blockIdx.y, q0 = blockIdx.x * 64;
    const int b = bh >> 4, h = bh & 15;

    const float M = __expf(fminf(sml[h], MAX_SCALE_MUL)) * LOG2E;

    const int sr = wave * 16 + (lane >> 3);
    const int sc = lane & 7;
    const int sg = sc ^ (sr & 7);               // swizzled global chunk
    const int swz8 = rr & 7;

    // Q B-fragments direct from global: B[n=q=rr][k=d=quad*8+j]
    const size_t qrow = (size_t)bh * PL + q0 + wave * 16 + rr;
    const s16x8 qB0 = *(const s16x8*)(Qh + qrow * PD + quad * 8);
    const s16x8 qB1 = *(const s16x8*)(Qh + qrow * PD + 32 + quad * 8);

    f32x4 accO[4];
#pragma unroll
    for (int jd = 0; jd < 4; jd++) accO[jd] = (f32x4){0.f, 0.f, 0.f, 0.f};
    float lsum = 0.f;

    const int qglob = q0 + wave * 16 + rr;

    for (int kb = 0; kb < 16; kb++) {
        gl2lds16(Kh + ((size_t)bh * PL + kb * 64 + sr) * PD + sg * 8, &Ks[(wave * 16) * 64]);
        gl2lds16(Kh + ((size_t)bh * PL + kb * 64 + sr + 8) * PD + sg * 8, &Ks[(wave * 16 + 8) * 64]);
        gl2lds16(Vt + ((size_t)bh * PD + sr) * PL + kb * 64 + sg * 8, &Vs[(wave * 16) * 64]);
        gl2lds16(Vt + ((size_t)bh * PD + sr + 8) * PL + kb * 64 + sg * 8, &Vs[(wave * 16 + 8) * 64]);
        __syncthreads();

        // S^T subtiles (log2 domain via Q pre-scale)
        f32x4 sc4[4];
#pragma unroll
        for (int s = 0; s < 4; s++) {
            s16x8 kA0 = *(const s16x8*)&Ks[(s * 16 + rr) * 64 + ((0 + quad) ^ swz8) * 8];
            s16x8 kA1 = *(const s16x8*)&Ks[(s * 16 + rr) * 64 + ((4 + quad) ^ swz8) * 8];
            f32x4 z = (f32x4){0.f, 0.f, 0.f, 0.f};
            z = MFMA16(kA0, qB0, z);
            z = MFMA16(kA1, qB1, z);
            sc4[s] = z;
        }

        // p = exp2(s + bias*log2e - M); accumulate l in-thread
#pragma unroll
        for (int s = 0; s < 4; s++) {
            float4 bv = *(const float4*)(bias + (size_t)qglob * PL + kb * 64 + s * 16 + quad * 4);
            sc4[s][0] = EXP2(fmaf(bv.x, LOG2E, sc4[s][0] - M));
            sc4[s][1] = EXP2(fmaf(bv.y, LOG2E, sc4[s][1] - M));
            sc4[s][2] = EXP2(fmaf(bv.z, LOG2E, sc4[s][2] - M));
            sc4[s][3] = EXP2(fmaf(bv.w, LOG2E, sc4[s][3] - M));
            lsum += sc4[s][0] + sc4[s][1] + sc4[s][2] + sc4[s][3];
        }

        // P^T repack via wave-private LDS
#pragma unroll
        for (int s = 0; s < 4; s++) {
            unsigned p01 = (unsigned)f2bf(sc4[s][0]) | ((unsigned)f2bf(sc4[s][1]) << 16);
            unsigned p23 = (unsigned)f2bf(sc4[s][2]) | ((unsigned)f2bf(sc4[s][3]) << 16);
            *(uint2*)&Ps[wave][rr * 36 + s * 8 + quad * 2] = make_uint2(p01, p23);
        }
        s16x8 pB0 = *(const s16x8*)&Ps[wave][rr * 36 + quad * 4];
        s16x8 pB1 = *(const s16x8*)&Ps[wave][rr * 36 + 16 + quad * 4];

        // O^T += V^T . P^T
#pragma unroll
        for (int jd = 0; jd < 4; jd++) {
            s16x8 vA0 = *(const s16x8*)&Vs[(jd * 16 + rr) * 64 + ((0 + quad) ^ swz8) * 8];
            s16x8 vA1 = *(const s16x8*)&Vs[(jd * 16 + rr) * 64 + ((4 + quad) ^ swz8) * 8];
            accO[jd] = MFMA16(vA0, pB0, accO[jd]);
            accO[jd] = MFMA16(vA1, pB1, accO[jd]);
        }
        __syncthreads();
    }

    // final l reduction across quads (same q lives at same rr in all quads)
    lsum += __shfl_xor(lsum, 16);
    lsum += __shfl_xor(lsum, 32);
    float inv = 1.0f / lsum;

    // epilogue: O^T -> LDS -> coalesced (B,L,H,D) stores
#pragma unroll
    for (int jd = 0; jd < 4; jd++) {
        unsigned o01 = (unsigned)f2bf(accO[jd][0] * inv) | ((unsigned)f2bf(accO[jd][1] * inv) << 16);
        unsigned o23 = (unsigned)f2bf(accO[jd][2] * inv) | ((unsigned)f2bf(accO[jd][3] * inv) << 16);
        *(uint2*)&Ps[wave][rr * 36 + jd * 8 + quad * 2] = make_uint2(o01, o23);
    }
    const int lr = lane >> 2, cch = lane & 3;
    uint4 w0 = *(const uint4*)&Ps[wave][lr * 36 + cch * 8];
    uint4 w1 = *(const uint4*)&Ps[wave][lr * 36 + cch * 8 + 4];
    size_t ob = ((size_t)(b * PL + q0 + wave * 16 + lr) * PC + h * PD);
    *(uint4*)(O + ob + cch * 16)     = w0;
    *(uint4*)(O + ob + cch * 16 + 8) = w1;
}

// ---------------------------------------------------------------------------
// Kernel 4: out-proj GEMM (bf16 MFMA). Out = Oh(8192x1024).Wph(1024x1024)^T + bp
// ---------------------------------------------------------------------------
__global__ __launch_bounds__(256) void gemm_proj_mfma(
    const unsigned short* __restrict__ Ah,
    const unsigned short* __restrict__ Wh,
    const float* __restrict__ bp, float* __restrict__ Out)
{
    __shared__ unsigned short As[128 * 32];
    __shared__ unsigned short Bs[128 * 32];
    const int tid  = threadIdx.x;
    const int wave = tid >> 6, lane = tid & 63;
    const int wm = wave & 1, wn = wave >> 1;
    const int quad = lane >> 4, rr = lane & 15;
    const int m0 = blockIdx.x * 128, n0 = blockIdx.y * 128;

    f32x4 acc[4][4];
#pragma unroll
    for (int i = 0; i < 4; i++)
#pragma unroll
        for (int j = 0; j < 4; j++) acc[i][j] = (f32x4){0.f, 0.f, 0.f, 0.f};

    const int rw = lane >> 2;
    const int cc = lane & 3;
    const int g  = cc ^ ((rw >> 1) & 3);
    const int srow = wave * 32 + rw;
    const unsigned short* gA0 = Ah + (size_t)(m0 + srow) * 1024 + g * 8;
    const unsigned short* gA1 = gA0 + (size_t)16 * 1024;
    const unsigned short* gB0 = Wh + (size_t)(n0 + srow) * 1024 + g * 8;
    const unsigned short* gB1 = gB0 + (size_t)16 * 1024;
    unsigned short* lA0 = &As[(wave * 32) * 32];
    unsigned short* lA1 = &As[(wave * 32 + 16) * 32];
    unsigned short* lB0 = &Bs[(wave * 32) * 32];
    unsigned short* lB1 = &Bs[(wave * 32 + 16) * 32];

    const int swz = (rr >> 1) & 3;
    const int coff = ((quad ^ swz) * 8);

    for (int k0 = 0; k0 < 1024; k0 += 32) {
        gl2lds16(gA0, lA0); gl2lds16(gA1, lA1);
        gl2lds16(gB0, lB0); gl2lds16(gB1, lB1);
        gA0 += 32; gA1 += 32; gB0 += 32; gB1 += 32;
        __syncthreads();

        s16x8 af[4], bf[4];
#pragma unroll
        for (int i = 0; i < 4; i++)
            af[i] = *(const s16x8*)&As[(wm * 64 + i * 16 + rr) * 32 + coff];
#pragma unroll
        for (int j = 0; j < 4; j++)
            bf[j] = *(const s16x8*)&Bs[(wn * 64 + j * 16 + rr) * 32 + coff];
#pragma unroll
        for (int i = 0; i < 4; i++)
#pragma unroll
            for (int j = 0; j < 4; j++)
                acc[i][j] = MFMA16(af[i], bf[j], acc[i][j]);
        __syncthreads();
    }

#pragma unroll
    for (int i = 0; i < 4; i++) {
        const int mb = m0 + wm * 64 + i * 16 + quad * 4;
#pragma unroll
        for (int j = 0; j < 4; j++) {
            const int n = n0 + wn * 64 + j * 16 + rr;
            const float bb = bp[n];
#pragma unroll
            for (int reg = 0; reg < 4; reg++)
                Out[(size_t)(mb + reg) * 1024 + n] = acc[i][j][reg] + bb;
        }
    }
}

// ---------------------------------------------------------------------------
extern "C" void kernel_launch(void* const* d_in, const int* in_sizes, int n_in,
                              void* d_out, int out_size, void* d_ws, size_t ws_size,
                              hipStream_t stream)
{
    const float* x         = (const float*)d_in[0];
    const float* freqs     = (const float*)d_in[1];
    const float* attn_bias = (const float*)d_in[2];
    const float* W_qkv     = (const float*)d_in[3];
    const float* q_bias    = (const float*)d_in[4];
    const float* v_bias    = (const float*)d_in[5];
    const float* sml       = (const float*)d_in[6];
    const float* W_proj    = (const float*)d_in[7];
    const float* b_proj    = (const float*)d_in[8];
    float* out = (float*)d_out;

    unsigned char* w = (unsigned char*)d_ws;
    const size_t MB = 1ull << 20;
    unsigned short* xh  = (unsigned short*)(w + 0);        // 16 MiB
    unsigned short* wqh = (unsigned short*)(w + 16 * MB);  //  6 MiB
    unsigned short* wph = (unsigned short*)(w + 22 * MB);  //  2 MiB
    unsigned short* Qh  = (unsigned short*)(w + 24 * MB);  // 16 MiB (in-place norm+rope)
    unsigned short* Kh  = (unsigned short*)(w + 40 * MB);  // 16 MiB (in-place norm+rope)
    unsigned short* Vh  = (unsigned short*)(w + 56 * MB);  // 16 MiB raw V (B,H,L,D)
    unsigned short* Vt  = (unsigned short*)(w + 72 * MB);  // 16 MiB (B,H,D,L)
    unsigned short* Oh  = (unsigned short*)(w + 88 * MB);  // 16 MiB (B,L,H,D)

    // 1. fused casts
    cast3_kernel<<<12288, 256, 0, stream>>>(x, W_qkv, W_proj, xh, wqh, wph);
    // 2. lean QKV projection
    gemm_qkv_lean<<<dim3(64, 24), 256, 0, stream>>>(xh, wqh, q_bias, v_bias, Qh, Kh, Vh);
    // 3. fused postprocess: Q/K norm+RoPE in place, V transpose
    postproc_kernel<<<34816, 256, 0, stream>>>(Qh, Kh, Vh, Vt, freqs, sml);
    // 4. flash attention (static-bound softmax, exp2 domain)
    attn_mfma<<<dim3(16, 128), 256, 0, stream>>>(Qh, Kh, Vt, attn_bias, sml, Oh);
    // 5. output projection
    gemm_proj_mfma<<<dim3(64, 8), 256, 0, stream>>>(Oh, wph, b_proj, out);
}